// Round 2
// baseline (5473.488 us; speedup 1.0000x reference)
//
#include <hip/hip_runtime.h>
#include <hip/hip_bf16.h>
#include <math.h>

// Problem constants
#define B_    8
#define NP_   784
#define ED_   1024
#define D_    512
#define H_    8
#define DH_   64
#define NPAT_ 1568
#define FF_   2048
#define L_    4
#define OUTD_ 1536
#define M_    (B_ * NP_)   // 6272

typedef __attribute__((ext_vector_type(8))) short bf16x8;
typedef __attribute__((ext_vector_type(4))) float f32x4;

// ---------------------------------------------------------------------------
// Split-bf16 MFMA GEMM: C[M,N] = A[M,K] @ W[N,K]^T + bias[N], optional GELU.
// fp32 inputs are split x = hi + lo (bf16 each, hi = truncated top-16 bits so
// x-hi is exact); C accumulates hi*hi + hi*lo + lo*hi in fp32 MFMA — dropped
// lo*lo term ~2^-16 relative => fp32-class accuracy at 3x MFMA cost.
//
// 128x128 tile, BK=32, 256 threads = 4 waves in 2x2, each wave 64x64 out
// (4x4 fragments of 16x16). LDS tiles stored in MFMA-fragment order:
// subtile s (16 rows x 32 k) occupies 512 shorts; lane l's 8 elements are
// contiguous at s*512 + l*8  =>  wave ds_read_b128 covers one contiguous
// 1 KB block (bank-conflict floor). Requires row = l&15, k = (l>>4)*8+j
// fragment layout for both A and B operands (B = W rows = output cols).
// ---------------------------------------------------------------------------
template <int ACT>
__global__ __launch_bounds__(256, 2) void gemm_mfma_kernel(
    const float* __restrict__ A, int lda,
    const float* __restrict__ W, int ldw,
    const float* __restrict__ bias,
    float* __restrict__ C, int ldc,
    int M, int N, int K)
{
    __shared__ short sAh[8 * 512];
    __shared__ short sAl[8 * 512];
    __shared__ short sBh[8 * 512];
    __shared__ short sBl[8 * 512];

    const int t    = threadIdx.x;
    const int lane = t & 63;
    const int wid  = t >> 6;
    const int wr   = wid >> 1;      // wave row-half (0..1)
    const int wc   = wid & 1;       // wave col-half (0..1)
    const int bm   = blockIdx.y * 128;
    const int bn   = blockIdx.x * 128;

    // staging: thread t covers tile-row srow = t>>1, k-half shalf = t&1 (16 fp32)
    const int srow  = t >> 1;
    const int shalf = t & 1;

    int arow = bm + srow; if (arow >= M) arow = M - 1;   // clamp (rows independent in MFMA)
    const float* aptr = A + (size_t)arow * lda + shalf * 16;
    const float* wptr = W + (size_t)(bn + srow) * ldw + shalf * 16;

    // LDS write base (elements): subtile (srow>>4), lane (srow&15)+(shalf*2+g)*16
    const int wbase = (srow >> 4) * 512 + (srow & 15) * 8 + shalf * 256;
    // g=0 at +0, g=1 at +128

    f32x4 acc[4][4];
#pragma unroll
    for (int i = 0; i < 4; i++)
#pragma unroll
        for (int j = 0; j < 4; j++) acc[i][j] = (f32x4)(0.0f);

    for (int k0 = 0; k0 < K; k0 += 32) {
        float4 av[4], wv[4];
#pragma unroll
        for (int q = 0; q < 4; q++) {
            av[q] = *(const float4*)(aptr + k0 + q * 4);
            wv[q] = *(const float4*)(wptr + k0 + q * 4);
        }
        __syncthreads();   // previous tile fully consumed

        // split + pack + LDS write (fragment order)
        {
            union { short s[16]; bf16x8 v[2]; } ah, al, wh, wl;
#pragma unroll
            for (int q = 0; q < 4; q++) {
                const float* ap = (const float*)&av[q];
                const float* wp = (const float*)&wv[q];
#pragma unroll
                for (int e = 0; e < 4; e++) {
                    int idx = q * 4 + e;
                    unsigned ab = __float_as_uint(ap[e]);
                    unsigned hb = ab & 0xFFFF0000u;
                    float ar = ap[e] - __uint_as_float(hb);
                    ah.s[idx] = (short)(ab >> 16);
                    al.s[idx] = (short)(__float_as_uint(ar) >> 16);
                    unsigned wb = __float_as_uint(wp[e]);
                    unsigned whb = wb & 0xFFFF0000u;
                    float wrr = wp[e] - __uint_as_float(whb);
                    wh.s[idx] = (short)(wb >> 16);
                    wl.s[idx] = (short)(__float_as_uint(wrr) >> 16);
                }
            }
            *(bf16x8*)&sAh[wbase]       = ah.v[0];
            *(bf16x8*)&sAh[wbase + 128] = ah.v[1];
            *(bf16x8*)&sAl[wbase]       = al.v[0];
            *(bf16x8*)&sAl[wbase + 128] = al.v[1];
            *(bf16x8*)&sBh[wbase]       = wh.v[0];
            *(bf16x8*)&sBh[wbase + 128] = wh.v[1];
            *(bf16x8*)&sBl[wbase]       = wl.v[0];
            *(bf16x8*)&sBl[wbase + 128] = wl.v[1];
        }
        __syncthreads();   // tile ready

        bf16x8 ahf[4], alf[4], bhf[4], blf[4];
#pragma unroll
        for (int i = 0; i < 4; i++) {
            int sa = (wr * 4 + i) * 512 + lane * 8;
            ahf[i] = *(const bf16x8*)&sAh[sa];
            alf[i] = *(const bf16x8*)&sAl[sa];
        }
#pragma unroll
        for (int j = 0; j < 4; j++) {
            int sb = (wc * 4 + j) * 512 + lane * 8;
            bhf[j] = *(const bf16x8*)&sBh[sb];
            blf[j] = *(const bf16x8*)&sBl[sb];
        }
#pragma unroll
        for (int i = 0; i < 4; i++)
#pragma unroll
            for (int j = 0; j < 4; j++) {
                acc[i][j] = __builtin_amdgcn_mfma_f32_16x16x32_bf16(ahf[i], bhf[j], acc[i][j], 0, 0, 0);
                acc[i][j] = __builtin_amdgcn_mfma_f32_16x16x32_bf16(ahf[i], blf[j], acc[i][j], 0, 0, 0);
                acc[i][j] = __builtin_amdgcn_mfma_f32_16x16x32_bf16(alf[i], bhf[j], acc[i][j], 0, 0, 0);
            }
    }

    // epilogue: D lane mapping col = lane&15, row = (lane>>4)*4 + r
    float bs[4];
#pragma unroll
    for (int j = 0; j < 4; j++)
        bs[j] = bias[bn + wc * 64 + j * 16 + (lane & 15)];

#pragma unroll
    for (int i = 0; i < 4; i++) {
        int row0 = bm + wr * 64 + i * 16 + ((lane >> 4) << 2);
#pragma unroll
        for (int r = 0; r < 4; r++) {
            int row = row0 + r;
            if (row < M) {
#pragma unroll
                for (int j = 0; j < 4; j++) {
                    int col = bn + wc * 64 + j * 16 + (lane & 15);
                    float v = acc[i][j][r] + bs[j];
                    if (ACT == 1) v = 0.5f * v * (1.0f + erff(v * 0.70710678118654752f));
                    C[(size_t)row * ldc + col] = v;
                }
            }
        }
    }
}

// ---------------------------------------------------------------------------
// Flash-style attention (fp32 vector). Block = (qtile 64 rows, head, batch).
// 4 lanes per q-row (16 dims each); KV staged in 32-row LDS tiles; online
// softmax. O written at ld 512 (head-concatenated).
// ---------------------------------------------------------------------------
__global__ __launch_bounds__(256) void attn_kernel(
    const float* __restrict__ Q, int ldq, size_t qStride,
    const float* __restrict__ K, int ldk, size_t kStride,
    const float* __restrict__ V, int ldv, size_t vStride,
    float* __restrict__ O,
    int qLen, int kvLen)
{
    __shared__ float Ks[32][64];
    __shared__ float Vs[32][64];

    const int t    = threadIdx.x;
    const int part = t & 3;
    const int r    = t >> 2;            // 0..63
    const int qt   = blockIdx.x;
    const int h    = blockIdx.y;
    const int b    = blockIdx.z;
    const int hoff = h * 64;
    const int qrow = qt * 64 + r;
    const bool qok = qrow < qLen;

    float q[16];
#pragma unroll
    for (int j = 0; j < 16; j++) q[j] = 0.0f;
    if (qok) {
        const float4* q4 = (const float4*)(Q + (size_t)b * qStride + (size_t)qrow * ldq + hoff + part * 16);
        float4 q0 = q4[0], q1 = q4[1], q2 = q4[2], q3 = q4[3];
        q[0] = q0.x; q[1] = q0.y; q[2] = q0.z; q[3] = q0.w;
        q[4] = q1.x; q[5] = q1.y; q[6] = q1.z; q[7] = q1.w;
        q[8] = q2.x; q[9] = q2.y; q[10] = q2.z; q[11] = q2.w;
        q[12] = q3.x; q[13] = q3.y; q[14] = q3.z; q[15] = q3.w;
    }

    float m = -1e30f, l = 0.0f;
    float o[16];
#pragma unroll
    for (int j = 0; j < 16; j++) o[j] = 0.0f;

    for (int kv0 = 0; kv0 < kvLen; kv0 += 32) {
        float4 kreg[2], vreg[2];
#pragma unroll
        for (int i = 0; i < 2; i++) {
            int idx  = i * 256 + t;
            int kr   = idx >> 4;
            int c4   = idx & 15;
            int krow = kv0 + kr;
            if (krow < kvLen) {
                kreg[i] = *(const float4*)(K + (size_t)b * kStride + (size_t)krow * ldk + hoff + c4 * 4);
                vreg[i] = *(const float4*)(V + (size_t)b * vStride + (size_t)krow * ldv + hoff + c4 * 4);
            } else {
                kreg[i] = make_float4(0.f, 0.f, 0.f, 0.f);
                vreg[i] = make_float4(0.f, 0.f, 0.f, 0.f);
            }
        }
        __syncthreads();
#pragma unroll
        for (int i = 0; i < 2; i++) {
            int idx = i * 256 + t;
            int kr  = idx >> 4;
            int c4  = idx & 15;
            *(float4*)&Ks[kr][c4 * 4] = kreg[i];
            *(float4*)&Vs[kr][c4 * 4] = vreg[i];
        }
        __syncthreads();

        float s[32];
#pragma unroll
        for (int k = 0; k < 32; k++) {
            const float4* kp = (const float4*)&Ks[k][part * 16];
            float4 k0 = kp[0], k1 = kp[1], k2 = kp[2], k3 = kp[3];
            float p;
            p = q[0] * k0.x;
            p = fmaf(q[1], k0.y, p);  p = fmaf(q[2], k0.z, p);  p = fmaf(q[3], k0.w, p);
            p = fmaf(q[4], k1.x, p);  p = fmaf(q[5], k1.y, p);  p = fmaf(q[6], k1.z, p);  p = fmaf(q[7], k1.w, p);
            p = fmaf(q[8], k2.x, p);  p = fmaf(q[9], k2.y, p);  p = fmaf(q[10], k2.z, p); p = fmaf(q[11], k2.w, p);
            p = fmaf(q[12], k3.x, p); p = fmaf(q[13], k3.y, p); p = fmaf(q[14], k3.z, p); p = fmaf(q[15], k3.w, p);
            p += __shfl_xor(p, 1);
            p += __shfl_xor(p, 2);
            s[k] = (kv0 + k < kvLen) ? p * 0.125f : -1e30f;
        }

        float tmax = s[0];
#pragma unroll
        for (int k = 1; k < 32; k++) tmax = fmaxf(tmax, s[k]);
        float mnew  = fmaxf(m, tmax);
        float alpha = expf(m - mnew);
        l *= alpha;
#pragma unroll
        for (int j = 0; j < 16; j++) o[j] *= alpha;

#pragma unroll
        for (int k = 0; k < 32; k++) {
            float p = expf(s[k] - mnew);
            l += p;
            const float4* vp = (const float4*)&Vs[k][part * 16];
            float4 v0 = vp[0], v1 = vp[1], v2 = vp[2], v3 = vp[3];
            o[0]  = fmaf(p, v0.x, o[0]);  o[1]  = fmaf(p, v0.y, o[1]);
            o[2]  = fmaf(p, v0.z, o[2]);  o[3]  = fmaf(p, v0.w, o[3]);
            o[4]  = fmaf(p, v1.x, o[4]);  o[5]  = fmaf(p, v1.y, o[5]);
            o[6]  = fmaf(p, v1.z, o[6]);  o[7]  = fmaf(p, v1.w, o[7]);
            o[8]  = fmaf(p, v2.x, o[8]);  o[9]  = fmaf(p, v2.y, o[9]);
            o[10] = fmaf(p, v2.z, o[10]); o[11] = fmaf(p, v2.w, o[11]);
            o[12] = fmaf(p, v3.x, o[12]); o[13] = fmaf(p, v3.y, o[13]);
            o[14] = fmaf(p, v3.z, o[14]); o[15] = fmaf(p, v3.w, o[15]);
        }
        m = mnew;
        __syncthreads();
    }

    if (qok) {
        float inv = 1.0f / l;
        float4* o4 = (float4*)(O + ((size_t)b * qLen + qrow) * 512 + hoff + part * 16);
        o4[0] = make_float4(o[0] * inv, o[1] * inv, o[2] * inv, o[3] * inv);
        o4[1] = make_float4(o[4] * inv, o[5] * inv, o[6] * inv, o[7] * inv);
        o4[2] = make_float4(o[8] * inv, o[9] * inv, o[10] * inv, o[11] * inv);
        o4[3] = make_float4(o[12] * inv, o[13] * inv, o[14] * inv, o[15] * inv);
    }
}

// ---------------------------------------------------------------------------
// LayerNorm over D=512: out = LN(a + res) * w + b. One wave per row.
// ---------------------------------------------------------------------------
__global__ __launch_bounds__(256) void ln_kernel(
    const float* __restrict__ a, const float* __restrict__ res,
    const float* __restrict__ w, const float* __restrict__ bb,
    float* __restrict__ out, int M)
{
    const int wid  = threadIdx.x >> 6;
    const int lane = threadIdx.x & 63;
    const int row  = blockIdx.x * 4 + wid;
    if (row >= M) return;

    const float* ap = a + (size_t)row * 512 + lane * 8;
    float4 x0 = *(const float4*)ap;
    float4 x1 = *(const float4*)(ap + 4);
    float v[8] = {x0.x, x0.y, x0.z, x0.w, x1.x, x1.y, x1.z, x1.w};
    if (res) {
        const float* rp = res + (size_t)row * 512 + lane * 8;
        float4 r0 = *(const float4*)rp;
        float4 r1 = *(const float4*)(rp + 4);
        v[0] += r0.x; v[1] += r0.y; v[2] += r0.z; v[3] += r0.w;
        v[4] += r1.x; v[5] += r1.y; v[6] += r1.z; v[7] += r1.w;
    }
    float sum = 0.f, sq = 0.f;
#pragma unroll
    for (int j = 0; j < 8; j++) { sum += v[j]; sq = fmaf(v[j], v[j], sq); }
#pragma unroll
    for (int off = 1; off < 64; off <<= 1) {
        sum += __shfl_xor(sum, off);
        sq  += __shfl_xor(sq, off);
    }
    float mean = sum * (1.0f / 512.0f);
    float var  = sq * (1.0f / 512.0f) - mean * mean;
    float rstd = 1.0f / sqrtf(var + 1e-5f);

    const float* wp = w + lane * 8;
    const float* bp = bb + lane * 8;
    float ov[8];
#pragma unroll
    for (int j = 0; j < 8; j++) ov[j] = (v[j] - mean) * rstd * wp[j] + bp[j];
    float* op = out + (size_t)row * 512 + lane * 8;
    *(float4*)op       = make_float4(ov[0], ov[1], ov[2], ov[3]);
    *(float4*)(op + 4) = make_float4(ov[4], ov[5], ov[6], ov[7]);
}

// ---------------------------------------------------------------------------
// Sin/cos positional embedding.
// ---------------------------------------------------------------------------
__global__ __launch_bounds__(256) void posembed_kernel(float* __restrict__ mem)
{
    int idx = blockIdx.x * 256 + threadIdx.x;
    if (idx >= NPAT_ * 256) return;
    int pos = idx >> 8;
    int i   = idx & 255;
    float div = expf((float)(2 * i) * (-9.21034037197618f / 512.0f));
    float ang = (float)pos * div;
    mem[(size_t)pos * 512 + 2 * i]     = sinf(ang);
    mem[(size_t)pos * 512 + 2 * i + 1] = cosf(ang);
}

// ---------------------------------------------------------------------------
// Scatter: winner pass (last p wins per (b, slot)) then patch writes.
// ---------------------------------------------------------------------------
__global__ __launch_bounds__(256) void winner_kernel(
    const int* __restrict__ mask, int* __restrict__ winner)
{
    int idx = blockIdx.x * 256 + threadIdx.x;
    if (idx >= B_ * NP_) return;
    int b = idx / NP_;
    atomicMax(&winner[b * NPAT_ + mask[idx]], idx % NP_);
}

__global__ __launch_bounds__(256) void scatter_kernel(
    const float* __restrict__ pred, const int* __restrict__ mask,
    const int* __restrict__ winner, float* __restrict__ out)
{
    int idx = blockIdx.x * 256 + threadIdx.x;
    if (idx >= B_ * NP_ * OUTD_) return;
    int e  = idx % OUTD_;
    int bp = idx / OUTD_;
    int p  = bp % NP_;
    int b  = bp / NP_;
    int mv = mask[b * NP_ + p];
    if (winner[b * NPAT_ + mv] != p) return;

    int f  = e / 768;
    int rm = e % 768;
    int c  = rm / 256;
    int r2 = rm % 256;
    int ph = r2 / 16;
    int pw = r2 % 16;
    int tt = mv / 196;
    int ss = mv % 196;
    int hi = ss / 14;
    int wi = ss % 14;

    size_t dst = ((size_t)((b * 16 + tt * 2 + f) * 3 + c)) * (224 * 224)
               + (size_t)(hi * 16 + ph) * 224 + (wi * 16 + pw);
    out[dst] = pred[(size_t)bp * OUTD_ + e];
}

// ---------------------------------------------------------------------------
extern "C" void kernel_launch(void* const* d_in, const int* in_sizes, int n_in,
                              void* d_out, int out_size, void* d_ws, size_t ws_size,
                              hipStream_t stream)
{
    const float* z       = (const float*)d_in[0];
    const int*   mask    = (const int*)d_in[1];
    const float* embed_w = (const float*)d_in[2];
    const float* embed_b = (const float*)d_in[3];
    const float* sa_qkv_w = (const float*)d_in[4];
    const float* sa_qkv_b = (const float*)d_in[5];
    const float* sa_out_w = (const float*)d_in[6];
    const float* sa_out_b = (const float*)d_in[7];
    const float* ca_qkv_w = (const float*)d_in[8];
    const float* ca_qkv_b = (const float*)d_in[9];
    const float* ca_out_w = (const float*)d_in[10];
    const float* ca_out_b = (const float*)d_in[11];
    const float* ff1_w = (const float*)d_in[12];
    const float* ff1_b = (const float*)d_in[13];
    const float* ff2_w = (const float*)d_in[14];
    const float* ff2_b = (const float*)d_in[15];
    const float* ln1_w = (const float*)d_in[16];
    const float* ln1_b = (const float*)d_in[17];
    const float* ln2_w = (const float*)d_in[18];
    const float* ln2_b = (const float*)d_in[19];
    const float* ln3_w = (const float*)d_in[20];
    const float* ln3_b = (const float*)d_in[21];
    const float* norm_w = (const float*)d_in[22];
    const float* norm_b = (const float*)d_in[23];
    const float* pred_w = (const float*)d_in[24];
    const float* pred_b = (const float*)d_in[25];

    float* ws  = (float*)d_ws;
    float* x   = ws;                          // [6272, 512]
    float* y   = x   + (size_t)M_ * 512;      // [6272, 2048]
    float* qkv = y   + (size_t)M_ * 2048;     // [6272, 1536]
    float* att = qkv + (size_t)M_ * 1536;     // [6272, 512]
    float* mem = att + (size_t)M_ * 512;      // [1568, 512]
    float* ckv = mem + (size_t)NPAT_ * 512;   // [1568, 1024]
    int* winner = (int*)(ckv + (size_t)NPAT_ * 1024);   // [8, 1568]

    posembed_kernel<<<NPAT_, 256, 0, stream>>>(mem);

    gemm_mfma_kernel<0><<<dim3(512 / 128, M_ / 128), 256, 0, stream>>>(
        z, ED_, embed_w, ED_, embed_b, x, 512, M_, 512, ED_);

    for (int l = 0; l < L_; l++) {
        const float* saw = sa_qkv_w + (size_t)l * 1536 * 512;
        const float* sab = sa_qkv_b + (size_t)l * 1536;
        const float* sow = sa_out_w + (size_t)l * 512 * 512;
        const float* sob = sa_out_b + (size_t)l * 512;
        const float* caw = ca_qkv_w + (size_t)l * 1536 * 512;
        const float* cab = ca_qkv_b + (size_t)l * 1536;
        const float* cow = ca_out_w + (size_t)l * 512 * 512;
        const float* cob = ca_out_b + (size_t)l * 512;
        const float* f1w = ff1_w + (size_t)l * 2048 * 512;
        const float* f1b = ff1_b + (size_t)l * 2048;
        const float* f2w = ff2_w + (size_t)l * 512 * 2048;
        const float* f2b = ff2_b + (size_t)l * 512;

        // ---- self-attention ----
        gemm_mfma_kernel<0><<<dim3(1536 / 128, M_ / 128), 256, 0, stream>>>(
            x, 512, saw, 512, sab, qkv, 1536, M_, 1536, 512);
        attn_kernel<<<dim3(13, H_, B_), 256, 0, stream>>>(
            qkv, 1536, (size_t)NP_ * 1536,
            qkv + 512, 1536, (size_t)NP_ * 1536,
            qkv + 1024, 1536, (size_t)NP_ * 1536,
            att, NP_, NP_);
        gemm_mfma_kernel<0><<<dim3(512 / 128, M_ / 128), 256, 0, stream>>>(
            att, 512, sow, 512, sob, y, 512, M_, 512, 512);
        ln_kernel<<<(M_ + 3) / 4, 256, 0, stream>>>(
            y, x, ln1_w + l * 512, ln1_b + l * 512, x, M_);

        // ---- cross-attention (K/V batch-shared: computed once over NPAT) ----
        gemm_mfma_kernel<0><<<dim3(512 / 128, M_ / 128), 256, 0, stream>>>(
            x, 512, caw, 512, cab, qkv, 512, M_, 512, 512);
        gemm_mfma_kernel<0><<<dim3(1024 / 128, (NPAT_ + 127) / 128), 256, 0, stream>>>(
            mem, 512, caw + 512 * 512, 512, cab + 512, ckv, 1024, NPAT_, 1024, 512);
        attn_kernel<<<dim3(13, H_, B_), 256, 0, stream>>>(
            qkv, 512, (size_t)NP_ * 512,
            ckv, 1024, (size_t)0,
            ckv + 512, 1024, (size_t)0,
            att, NP_, NPAT_);
        gemm_mfma_kernel<0><<<dim3(512 / 128, M_ / 128), 256, 0, stream>>>(
            att, 512, cow, 512, cob, y, 512, M_, 512, 512);
        ln_kernel<<<(M_ + 3) / 4, 256, 0, stream>>>(
            y, x, ln2_w + l * 512, ln2_b + l * 512, x, M_);

        // ---- feed-forward ----
        gemm_mfma_kernel<1><<<dim3(2048 / 128, M_ / 128), 256, 0, stream>>>(
            x, 512, f1w, 512, f1b, y, 2048, M_, 2048, 512);
        gemm_mfma_kernel<0><<<dim3(512 / 128, M_ / 128), 256, 0, stream>>>(
            y, 2048, f2w, 2048, f2b, att, 512, M_, 512, 2048);
        ln_kernel<<<(M_ + 3) / 4, 256, 0, stream>>>(
            att, x, ln3_w + l * 512, ln3_b + l * 512, x, M_);
    }

    ln_kernel<<<(M_ + 3) / 4, 256, 0, stream>>>(x, nullptr, norm_w, norm_b, x, M_);
    gemm_mfma_kernel<0><<<dim3(1536 / 128, M_ / 128), 256, 0, stream>>>(
        x, 512, pred_w, 512, pred_b, qkv, 1536, M_, 1536, 512);

    hipMemsetAsync(d_out, 0, (size_t)out_size * sizeof(float), stream);
    hipMemsetAsync(winner, 0xFF, (size_t)B_ * NPAT_ * sizeof(int), stream);
    winner_kernel<<<(B_ * NP_ + 255) / 256, 256, 0, stream>>>(mask, winner);
    scatter_kernel<<<(B_ * NP_ * OUTD_ + 255) / 256, 256, 0, stream>>>(
        qkv, mask, winner, (float*)d_out);
}

// Round 5
// 2757.456 us; speedup vs baseline: 1.9850x; 1.9850x over previous
//
#include <hip/hip_runtime.h>
#include <hip/hip_bf16.h>
#include <math.h>

// Problem constants
#define B_    8
#define NP_   784
#define ED_   1024
#define D_    512
#define H_    8
#define DH_   64
#define NPAT_ 1568
#define FF_   2048
#define L_    4
#define OUTD_ 1536
#define M_    (B_ * NP_)   // 6272

typedef __attribute__((ext_vector_type(8))) short bf16x8;
typedef __attribute__((ext_vector_type(4))) float f32x4;

// split x = hi + lo, both bf16 (truncation: x - hi exact, dropped term ~2^-16 rel)
static __device__ inline void split_bf16(float x, unsigned short& h, unsigned short& l)
{
    unsigned bits = __float_as_uint(x);
    h = (unsigned short)(bits >> 16);
    float r = x - __uint_as_float(bits & 0xFFFF0000u);
    l = (unsigned short)(__float_as_uint(r) >> 16);
}

// ---------------------------------------------------------------------------
// Split-bf16 MFMA GEMM: C[M,N] = A[M,K] @ W[N,K]^T + bias[N], optional GELU.
// (unchanged from round 2 — validated, ~37.6us avg/dispatch)
// ---------------------------------------------------------------------------
template <int ACT>
__global__ __launch_bounds__(256, 2) void gemm_mfma_kernel(
    const float* __restrict__ A, int lda,
    const float* __restrict__ W, int ldw,
    const float* __restrict__ bias,
    float* __restrict__ C, int ldc,
    int M, int N, int K)
{
    __shared__ short sAh[8 * 512];
    __shared__ short sAl[8 * 512];
    __shared__ short sBh[8 * 512];
    __shared__ short sBl[8 * 512];

    const int t    = threadIdx.x;
    const int lane = t & 63;
    const int wid  = t >> 6;
    const int wr   = wid >> 1;
    const int wc   = wid & 1;
    const int bm   = blockIdx.y * 128;
    const int bn   = blockIdx.x * 128;

    const int srow  = t >> 1;
    const int shalf = t & 1;

    int arow = bm + srow; if (arow >= M) arow = M - 1;
    const float* aptr = A + (size_t)arow * lda + shalf * 16;
    const float* wptr = W + (size_t)(bn + srow) * ldw + shalf * 16;

    const int wbase = (srow >> 4) * 512 + (srow & 15) * 8 + shalf * 256;

    f32x4 acc[4][4];
#pragma unroll
    for (int i = 0; i < 4; i++)
#pragma unroll
        for (int j = 0; j < 4; j++) acc[i][j] = (f32x4)(0.0f);

    for (int k0 = 0; k0 < K; k0 += 32) {
        float4 av[4], wv[4];
#pragma unroll
        for (int q = 0; q < 4; q++) {
            av[q] = *(const float4*)(aptr + k0 + q * 4);
            wv[q] = *(const float4*)(wptr + k0 + q * 4);
        }
        __syncthreads();

        {
            union { short s[16]; bf16x8 v[2]; } ah, al, wh, wl;
#pragma unroll
            for (int q = 0; q < 4; q++) {
                const float* ap = (const float*)&av[q];
                const float* wp = (const float*)&wv[q];
#pragma unroll
                for (int e = 0; e < 4; e++) {
                    int idx = q * 4 + e;
                    unsigned short hh, ll;
                    split_bf16(ap[e], hh, ll);
                    ah.s[idx] = (short)hh; al.s[idx] = (short)ll;
                    split_bf16(wp[e], hh, ll);
                    wh.s[idx] = (short)hh; wl.s[idx] = (short)ll;
                }
            }
            *(bf16x8*)&sAh[wbase]       = ah.v[0];
            *(bf16x8*)&sAh[wbase + 128] = ah.v[1];
            *(bf16x8*)&sAl[wbase]       = al.v[0];
            *(bf16x8*)&sAl[wbase + 128] = al.v[1];
            *(bf16x8*)&sBh[wbase]       = wh.v[0];
            *(bf16x8*)&sBh[wbase + 128] = wh.v[1];
            *(bf16x8*)&sBl[wbase]       = wl.v[0];
            *(bf16x8*)&sBl[wbase + 128] = wl.v[1];
        }
        __syncthreads();

        bf16x8 ahf[4], alf[4], bhf[4], blf[4];
#pragma unroll
        for (int i = 0; i < 4; i++) {
            int sa = (wr * 4 + i) * 512 + lane * 8;
            ahf[i] = *(const bf16x8*)&sAh[sa];
            alf[i] = *(const bf16x8*)&sAl[sa];
        }
#pragma unroll
        for (int j = 0; j < 4; j++) {
            int sb = (wc * 4 + j) * 512 + lane * 8;
            bhf[j] = *(const bf16x8*)&sBh[sb];
            blf[j] = *(const bf16x8*)&sBl[sb];
        }
#pragma unroll
        for (int i = 0; i < 4; i++)
#pragma unroll
            for (int j = 0; j < 4; j++) {
                acc[i][j] = __builtin_amdgcn_mfma_f32_16x16x32_bf16(ahf[i], bhf[j], acc[i][j], 0, 0, 0);
                acc[i][j] = __builtin_amdgcn_mfma_f32_16x16x32_bf16(ahf[i], blf[j], acc[i][j], 0, 0, 0);
                acc[i][j] = __builtin_amdgcn_mfma_f32_16x16x32_bf16(alf[i], bhf[j], acc[i][j], 0, 0, 0);
            }
    }

    float bs[4];
#pragma unroll
    for (int j = 0; j < 4; j++)
        bs[j] = bias[bn + wc * 64 + j * 16 + (lane & 15)];

#pragma unroll
    for (int i = 0; i < 4; i++) {
        int row0 = bm + wr * 64 + i * 16 + ((lane >> 4) << 2);
#pragma unroll
        for (int r = 0; r < 4; r++) {
            int row = row0 + r;
            if (row < M) {
#pragma unroll
                for (int j = 0; j < 4; j++) {
                    int col = bn + wc * 64 + j * 16 + (lane & 15);
                    float v = acc[i][j][r] + bs[j];
                    if (ACT == 1) v = 0.5f * v * (1.0f + erff(v * 0.70710678118654752f));
                    C[(size_t)row * ldc + col] = v;
                }
            }
        }
    }
}

// ---------------------------------------------------------------------------
// MFMA flash attention, split-bf16 3-term (fp32-class accuracy).
// Block = 256 thr (4 waves) = one (b, h, 64-q-row tile). Each wave owns 16
// q rows. KV iterated in 64-row tiles.
//   QK^T swapped: S^T = K*Q^T  (A = K in A-frag LDS order, B = Q in regs)
//     -> lane holds 16 scores, all for q = lane&15: softmax reduce = local
//        max/sum + shfl_xor(16,32).
//   P -> P_lds[q][kv] bf16 hi/lo, b64 writes, XOR-swizzled (^(q&7)<<4),
//        wave-private (no barrier).
//   PV straight: O = P*V (A = P from P_lds, B = V staged in B-frag order).
// O layout: row q = (lane>>4)*4+r, col dh = 16f + (lane&15).
// ---------------------------------------------------------------------------
__global__ __launch_bounds__(256, 3) void attn_mfma_kernel(
    const float* __restrict__ Q, int ldq, size_t qStride,
    const float* __restrict__ K, int ldk, size_t kStride,
    const float* __restrict__ V, int ldv, size_t vStride,
    float* __restrict__ O,
    int qLen, int kvLen)
{
    __shared__ short sKh[4096], sKl[4096], sVh[4096], sVl[4096];   // 64kv x 64dh each
    __shared__ short sP[4][2048];                                   // per wave: hi 1K, lo 1K shorts

    const int t    = threadIdx.x;
    const int lane = t & 63;
    const int wid  = t >> 6;
    const int g    = lane >> 4;
    const int l15  = lane & 15;
    const int qt   = blockIdx.x;
    const int h    = blockIdx.y;
    const int b    = blockIdx.z;
    const int hoff = h * 64;

    // ---- Q fragments (B-operand layout: col=q=l15, k=dh=g*8+j+32ks) ----
    int qrow = qt * 64 + wid * 16 + l15;
    int qcl  = qrow < qLen ? qrow : qLen - 1;
    const float* qp = Q + (size_t)b * qStride + (size_t)qcl * ldq + hoff + g * 8;
    bf16x8 qh[2], ql[2];
#pragma unroll
    for (int ks = 0; ks < 2; ks++) {
        float4 x0 = *(const float4*)(qp + ks * 32);
        float4 x1 = *(const float4*)(qp + ks * 32 + 4);
        union { float f[8]; } xv;
        xv.f[0]=x0.x; xv.f[1]=x0.y; xv.f[2]=x0.z; xv.f[3]=x0.w;
        xv.f[4]=x1.x; xv.f[5]=x1.y; xv.f[6]=x1.z; xv.f[7]=x1.w;
        union { short s[8]; bf16x8 v; } hi, lo;
#pragma unroll
        for (int e = 0; e < 8; e++) {
            unsigned short hh, ll;
            split_bf16(xv.f[e], hh, ll);
            hi.s[e] = (short)hh; lo.s[e] = (short)ll;
        }
        qh[ks] = hi.v; ql[ks] = lo.v;
    }

    f32x4 o[4];
#pragma unroll
    for (int f = 0; f < 4; f++) o[f] = (f32x4)(0.0f);
    float m = -1e30f, lsum = 0.0f;

    // staging maps
    const int kvK = t >> 2;            // K: one kv row, 16 dh
    const int dhK = (t & 3) * 16;
    const int kwoff = ((dhK >> 5) * 4 + (kvK >> 4)) * 512 + (kvK & 15) * 8 + ((dhK & 31) >> 3) * 128;
    const int kvV = (t >> 4) * 4;      // V: 4 kv rows x 4 dh
    const int dhV = (t & 15) * 4;

    char* const phw = (char*)&sP[wid][0];
    char* const plw = phw + 2048;

    for (int kv0 = 0; kv0 < kvLen; kv0 += 64) {
        // ---- global loads (regs) ----
        int krow = kv0 + kvK; if (krow >= kvLen) krow = kvLen - 1;
        const float* kp = K + (size_t)b * kStride + (size_t)krow * ldk + hoff + dhK;
        float4 kx[4];
#pragma unroll
        for (int q = 0; q < 4; q++) kx[q] = *(const float4*)(kp + q * 4);
        float4 vx[4];
#pragma unroll
        for (int i = 0; i < 4; i++) {
            int vrow = kv0 + kvV + i; if (vrow >= kvLen) vrow = kvLen - 1;
            vx[i] = *(const float4*)(V + (size_t)b * vStride + (size_t)vrow * ldv + hoff + dhV);
        }
        __syncthreads();   // prev tile fully consumed

        // ---- stage K (A-frag order) ----
        {
            union { short s[16]; bf16x8 v[2]; } kh, kl;
#pragma unroll
            for (int q = 0; q < 4; q++) {
                const float* fp = (const float*)&kx[q];
#pragma unroll
                for (int e = 0; e < 4; e++) {
                    unsigned short hh, ll;
                    split_bf16(fp[e], hh, ll);
                    kh.s[q * 4 + e] = (short)hh; kl.s[q * 4 + e] = (short)ll;
                }
            }
            *(bf16x8*)&sKh[kwoff]       = kh.v[0];
            *(bf16x8*)&sKh[kwoff + 128] = kh.v[1];
            *(bf16x8*)&sKl[kwoff]       = kl.v[0];
            *(bf16x8*)&sKl[kwoff + 128] = kl.v[1];
        }
        // ---- stage V (B-frag order, transpose-pack along kv) ----
        {
            union { float4 f4; float a[4]; } vu[4];
#pragma unroll
            for (int i = 0; i < 4; i++) vu[i].f4 = vx[i];
#pragma unroll
            for (int c = 0; c < 4; c++) {
                int dh = dhV + c;
                unsigned short h0,h1,h2,h3, l0,l1,l2,l3;
                split_bf16(vu[0].a[c], h0, l0);
                split_bf16(vu[1].a[c], h1, l1);
                split_bf16(vu[2].a[c], h2, l2);
                split_bf16(vu[3].a[c], h3, l3);
                uint2 uh, ul;
                uh.x = (unsigned)h0 | ((unsigned)h1 << 16);
                uh.y = (unsigned)h2 | ((unsigned)h3 << 16);
                ul.x = (unsigned)l0 | ((unsigned)l1 << 16);
                ul.y = (unsigned)l2 | ((unsigned)l3 << 16);
                int voff = ((kvV >> 5) * 4 + (dh >> 4)) * 1024 + (dh & 15) * 16
                         + ((kvV & 31) >> 3) * 256 + (kvV & 7) * 2;
                *(uint2*)((char*)sVh + voff) = uh;
                *(uint2*)((char*)sVl + voff) = ul;
            }
        }
        __syncthreads();   // tile ready

        // ---- QK^T (swapped): S^T[kv][q] ----
        f32x4 s[4];
#pragma unroll
        for (int f = 0; f < 4; f++) s[f] = (f32x4)(0.0f);
#pragma unroll
        for (int f = 0; f < 4; f++)
#pragma unroll
            for (int ks = 0; ks < 2; ks++) {
                int off = (ks * 4 + f) * 512 + lane * 8;
                bf16x8 kh8 = *(const bf16x8*)&sKh[off];
                bf16x8 kl8 = *(const bf16x8*)&sKl[off];
                s[f] = __builtin_amdgcn_mfma_f32_16x16x32_bf16(kh8, qh[ks], s[f], 0, 0, 0);
                s[f] = __builtin_amdgcn_mfma_f32_16x16x32_bf16(kh8, ql[ks], s[f], 0, 0, 0);
                s[f] = __builtin_amdgcn_mfma_f32_16x16x32_bf16(kl8, qh[ks], s[f], 0, 0, 0);
            }

        // ---- softmax (per q = l15) ----
        float tmax = -1e30f;
#pragma unroll
        for (int f = 0; f < 4; f++)
#pragma unroll
            for (int r = 0; r < 4; r++) {
                float sv = s[f][r] * 0.125f;
                int kvg = kv0 + 16 * f + g * 4 + r;
                sv = (kvg < kvLen) ? sv : -1e30f;
                s[f][r] = sv;
                tmax = fmaxf(tmax, sv);
            }
        tmax = fmaxf(tmax, __shfl_xor(tmax, 16));
        tmax = fmaxf(tmax, __shfl_xor(tmax, 32));
        float mnew  = fmaxf(m, tmax);
        float alpha = __expf(m - mnew);
        m = mnew;
        lsum *= alpha;

        // P = exp(S - m), split, pack, write to wave-private swizzled P_lds
#pragma unroll
        for (int f = 0; f < 4; f++) {
            float p0 = __expf(s[f][0] - mnew);
            float p1 = __expf(s[f][1] - mnew);
            float p2 = __expf(s[f][2] - mnew);
            float p3 = __expf(s[f][3] - mnew);
            lsum += (p0 + p1) + (p2 + p3);
            unsigned short h0,h1,h2,h3, l0,l1,l2,l3;
            split_bf16(p0, h0, l0); split_bf16(p1, h1, l1);
            split_bf16(p2, h2, l2); split_bf16(p3, h3, l3);
            uint2 uh, ul;
            uh.x = (unsigned)h0 | ((unsigned)h1 << 16);
            uh.y = (unsigned)h2 | ((unsigned)h3 << 16);
            ul.x = (unsigned)l0 | ((unsigned)l1 << 16);
            ul.y = (unsigned)l2 | ((unsigned)l3 << 16);
            int wa = (l15 * 128 + f * 32 + g * 8) ^ ((l15 & 7) << 4);
            *(uint2*)(phw + wa) = uh;
            *(uint2*)(plw + wa) = ul;
        }

        // rescale O by alpha of its q rows (q = g*4+r lives at lane g*4+r)
        {
            float a0 = __shfl(alpha, g * 4 + 0);
            float a1 = __shfl(alpha, g * 4 + 1);
            float a2 = __shfl(alpha, g * 4 + 2);
            float a3 = __shfl(alpha, g * 4 + 3);
#pragma unroll
            for (int f = 0; f < 4; f++) {
                o[f][0] *= a0; o[f][1] *= a1; o[f][2] *= a2; o[f][3] *= a3;
            }
        }

        // ---- PV: O += P * V ----
#pragma unroll
        for (int ks = 0; ks < 2; ks++) {
            int pa = (l15 * 128 + ks * 64 + g * 16) ^ ((l15 & 7) << 4);
            bf16x8 p_h = *(const bf16x8*)(phw + pa);
            bf16x8 p_l = *(const bf16x8*)(plw + pa);
#pragma unroll
            for (int f = 0; f < 4; f++) {
                int off = (ks * 4 + f) * 512 + lane * 8;
                bf16x8 vh8 = *(const bf16x8*)&sVh[off];
                bf16x8 vl8 = *(const bf16x8*)&sVl[off];
                o[f] = __builtin_amdgcn_mfma_f32_16x16x32_bf16(p_h, vh8, o[f], 0, 0, 0);
                o[f] = __builtin_amdgcn_mfma_f32_16x16x32_bf16(p_h, vl8, o[f], 0, 0, 0);
                o[f] = __builtin_amdgcn_mfma_f32_16x16x32_bf16(p_l, vh8, o[f], 0, 0, 0);
            }
        }
    }

    // ---- epilogue ----
    lsum += __shfl_xor(lsum, 16);
    lsum += __shfl_xor(lsum, 32);
    float linv = 1.0f / lsum;
    float lr0 = __shfl(linv, g * 4 + 0);
    float lr1 = __shfl(linv, g * 4 + 1);
    float lr2 = __shfl(linv, g * 4 + 2);
    float lr3 = __shfl(linv, g * 4 + 3);
    float lr[4] = {lr0, lr1, lr2, lr3};

    int row0 = qt * 64 + wid * 16 + g * 4;
#pragma unroll
    for (int r = 0; r < 4; r++) {
        int row = row0 + r;
        if (row < qLen) {
            float* op = O + ((size_t)b * qLen + row) * 512 + hoff + l15;
#pragma unroll
            for (int f = 0; f < 4; f++)
                op[f * 16] = o[f][r] * lr[r];
        }
    }
}

// ---------------------------------------------------------------------------
// LayerNorm over D=512: out = LN(a + res) * w + b. One wave per row.
// ---------------------------------------------------------------------------
__global__ __launch_bounds__(256) void ln_kernel(
    const float* __restrict__ a, const float* __restrict__ res,
    const float* __restrict__ w, const float* __restrict__ bb,
    float* __restrict__ out, int M)
{
    const int wid  = threadIdx.x >> 6;
    const int lane = threadIdx.x & 63;
    const int row  = blockIdx.x * 4 + wid;
    if (row >= M) return;

    const float* ap = a + (size_t)row * 512 + lane * 8;
    float4 x0 = *(const float4*)ap;
    float4 x1 = *(const float4*)(ap + 4);
    float v[8] = {x0.x, x0.y, x0.z, x0.w, x1.x, x1.y, x1.z, x1.w};
    if (res) {
        const float* rp = res + (size_t)row * 512 + lane * 8;
        float4 r0 = *(const float4*)rp;
        float4 r1 = *(const float4*)(rp + 4);
        v[0] += r0.x; v[1] += r0.y; v[2] += r0.z; v[3] += r0.w;
        v[4] += r1.x; v[5] += r1.y; v[6] += r1.z; v[7] += r1.w;
    }
    float sum = 0.f, sq = 0.f;
#pragma unroll
    for (int j = 0; j < 8; j++) { sum += v[j]; sq = fmaf(v[j], v[j], sq); }
#pragma unroll
    for (int off = 1; off < 64; off <<= 1) {
        sum += __shfl_xor(sum, off);
        sq  += __shfl_xor(sq, off);
    }
    float mean = sum * (1.0f / 512.0f);
    float var  = sq * (1.0f / 512.0f) - mean * mean;
    float rstd = 1.0f / sqrtf(var + 1e-5f);

    const float* wp = w + lane * 8;
    const float* bp = bb + lane * 8;
    float ov[8];
#pragma unroll
    for (int j = 0; j < 8; j++) ov[j] = (v[j] - mean) * rstd * wp[j] + bp[j];
    float* op = out + (size_t)row * 512 + lane * 8;
    *(float4*)op       = make_float4(ov[0], ov[1], ov[2], ov[3]);
    *(float4*)(op + 4) = make_float4(ov[4], ov[5], ov[6], ov[7]);
}

// ---------------------------------------------------------------------------
// Sin/cos positional embedding.
// ---------------------------------------------------------------------------
__global__ __launch_bounds__(256) void posembed_kernel(float* __restrict__ mem)
{
    int idx = blockIdx.x * 256 + threadIdx.x;
    if (idx >= NPAT_ * 256) return;
    int pos = idx >> 8;
    int i   = idx & 255;
    float div = expf((float)(2 * i) * (-9.21034037197618f / 512.0f));
    float ang = (float)pos * div;
    mem[(size_t)pos * 512 + 2 * i]     = sinf(ang);
    mem[(size_t)pos * 512 + 2 * i + 1] = cosf(ang);
}

// ---------------------------------------------------------------------------
// Scatter: winner pass (last p wins per (b, slot)) then patch writes.
// ---------------------------------------------------------------------------
__global__ __launch_bounds__(256) void winner_kernel(
    const int* __restrict__ mask, int* __restrict__ winner)
{
    int idx = blockIdx.x * 256 + threadIdx.x;
    if (idx >= B_ * NP_) return;
    int b = idx / NP_;
    atomicMax(&winner[b * NPAT_ + mask[idx]], idx % NP_);
}

__global__ __launch_bounds__(256) void scatter_kernel(
    const float* __restrict__ pred, const int* __restrict__ mask,
    const int* __restrict__ winner, float* __restrict__ out)
{
    int idx = blockIdx.x * 256 + threadIdx.x;
    if (idx >= B_ * NP_ * OUTD_) return;
    int e  = idx % OUTD_;
    int bp = idx / OUTD_;
    int p  = bp % NP_;
    int b  = bp / NP_;
    int mv = mask[b * NP_ + p];
    if (winner[b * NPAT_ + mv] != p) return;

    int f  = e / 768;
    int rm = e % 768;
    int c  = rm / 256;
    int r2 = rm % 256;
    int ph = r2 / 16;
    int pw = r2 % 16;
    int tt = mv / 196;
    int ss = mv % 196;
    int hi = ss / 14;
    int wi = ss % 14;

    size_t dst = ((size_t)((b * 16 + tt * 2 + f) * 3 + c)) * (224 * 224)
               + (size_t)(hi * 16 + ph) * 224 + (wi * 16 + pw);
    out[dst] = pred[(size_t)bp * OUTD_ + e];
}

// ---------------------------------------------------------------------------
extern "C" void kernel_launch(void* const* d_in, const int* in_sizes, int n_in,
                              void* d_out, int out_size, void* d_ws, size_t ws_size,
                              hipStream_t stream)
{
    const float* z       = (const float*)d_in[0];
    const int*   mask    = (const int*)d_in[1];
    const float* embed_w = (const float*)d_in[2];
    const float* embed_b = (const float*)d_in[3];
    const float* sa_qkv_w = (const float*)d_in[4];
    const float* sa_qkv_b = (const float*)d_in[5];
    const float* sa_out_w = (const float*)d_in[6];
    const float* sa_out_b = (const float*)d_in[7];
    const float* ca_qkv_w = (const float*)d_in[8];
    const float* ca_qkv_b = (const float*)d_in[9];
    const float* ca_out_w = (const float*)d_in[10];
    const float* ca_out_b = (const float*)d_in[11];
    const float* ff1_w = (const float*)d_in[12];
    const float* ff1_b = (const float*)d_in[13];
    const float* ff2_w = (const float*)d_in[14];
    const float* ff2_b = (const float*)d_in[15];
    const float* ln1_w = (const float*)d_in[16];
    const float* ln1_b = (const float*)d_in[17];
    const float* ln2_w = (const float*)d_in[18];
    const float* ln2_b = (const float*)d_in[19];
    const float* ln3_w = (const float*)d_in[20];
    const float* ln3_b = (const float*)d_in[21];
    const float* norm_w = (const float*)d_in[22];
    const float* norm_b = (const float*)d_in[23];
    const float* pred_w = (const float*)d_in[24];
    const float* pred_b = (const float*)d_in[25];

    float* ws  = (float*)d_ws;
    float* x   = ws;                          // [6272, 512]
    float* y   = x   + (size_t)M_ * 512;      // [6272, 2048]
    float* qkv = y   + (size_t)M_ * 2048;     // [6272, 1536]
    float* att = qkv + (size_t)M_ * 1536;     // [6272, 512]
    float* mem = att + (size_t)M_ * 512;      // [1568, 512]
    float* ckv = mem + (size_t)NPAT_ * 512;   // [1568, 1024]
    int* winner = (int*)(ckv + (size_t)NPAT_ * 1024);   // [8, 1568]

    posembed_kernel<<<NPAT_, 256, 0, stream>>>(mem);

    gemm_mfma_kernel<0><<<dim3(512 / 128, M_ / 128), 256, 0, stream>>>(
        z, ED_, embed_w, ED_, embed_b, x, 512, M_, 512, ED_);

    for (int l = 0; l < L_; l++) {
        const float* saw = sa_qkv_w + (size_t)l * 1536 * 512;
        const float* sab = sa_qkv_b + (size_t)l * 1536;
        const float* sow = sa_out_w + (size_t)l * 512 * 512;
        const float* sob = sa_out_b + (size_t)l * 512;
        const float* caw = ca_qkv_w + (size_t)l * 1536 * 512;
        const float* cab = ca_qkv_b + (size_t)l * 1536;
        const float* cow = ca_out_w + (size_t)l * 512 * 512;
        const float* cob = ca_out_b + (size_t)l * 512;
        const float* f1w = ff1_w + (size_t)l * 2048 * 512;
        const float* f1b = ff1_b + (size_t)l * 2048;
        const float* f2w = ff2_w + (size_t)l * 512 * 2048;
        const float* f2b = ff2_b + (size_t)l * 512;

        // ---- self-attention ----
        gemm_mfma_kernel<0><<<dim3(1536 / 128, M_ / 128), 256, 0, stream>>>(
            x, 512, saw, 512, sab, qkv, 1536, M_, 1536, 512);
        attn_mfma_kernel<<<dim3(13, H_, B_), 256, 0, stream>>>(
            qkv, 1536, (size_t)NP_ * 1536,
            qkv + 512, 1536, (size_t)NP_ * 1536,
            qkv + 1024, 1536, (size_t)NP_ * 1536,
            att, NP_, NP_);
        gemm_mfma_kernel<0><<<dim3(512 / 128, M_ / 128), 256, 0, stream>>>(
            att, 512, sow, 512, sob, y, 512, M_, 512, 512);
        ln_kernel<<<(M_ + 3) / 4, 256, 0, stream>>>(
            y, x, ln1_w + l * 512, ln1_b + l * 512, x, M_);

        // ---- cross-attention (K/V batch-shared: computed once over NPAT) ----
        gemm_mfma_kernel<0><<<dim3(512 / 128, M_ / 128), 256, 0, stream>>>(
            x, 512, caw, 512, cab, qkv, 512, M_, 512, 512);
        gemm_mfma_kernel<0><<<dim3(1024 / 128, (NPAT_ + 127) / 128), 256, 0, stream>>>(
            mem, 512, caw + 512 * 512, 512, cab + 512, ckv, 1024, NPAT_, 1024, 512);
        attn_mfma_kernel<<<dim3(13, H_, B_), 256, 0, stream>>>(
            qkv, 512, (size_t)NP_ * 512,
            ckv, 1024, (size_t)0,
            ckv + 512, 1024, (size_t)0,
            att, NP_, NPAT_);
        gemm_mfma_kernel<0><<<dim3(512 / 128, M_ / 128), 256, 0, stream>>>(
            att, 512, cow, 512, cob, y, 512, M_, 512, 512);
        ln_kernel<<<(M_ + 3) / 4, 256, 0, stream>>>(
            y, x, ln2_w + l * 512, ln2_b + l * 512, x, M_);

        // ---- feed-forward ----
        gemm_mfma_kernel<1><<<dim3(2048 / 128, M_ / 128), 256, 0, stream>>>(
            x, 512, f1w, 512, f1b, y, 2048, M_, 2048, 512);
        gemm_mfma_kernel<0><<<dim3(512 / 128, M_ / 128), 256, 0, stream>>>(
            y, 2048, f2w, 2048, f2b, att, 512, M_, 512, 2048);
        ln_kernel<<<(M_ + 3) / 4, 256, 0, stream>>>(
            att, x, ln3_w + l * 512, ln3_b + l * 512, x, M_);
    }

    ln_kernel<<<(M_ + 3) / 4, 256, 0, stream>>>(x, nullptr, norm_w, norm_b, x, M_);
    gemm_mfma_kernel<0><<<dim3(1536 / 128, M_ / 128), 256, 0, stream>>>(
        x, 512, pred_w, 512, pred_b, qkv, 1536, M_, 1536, 512);

    hipMemsetAsync(d_out, 0, (size_t)out_size * sizeof(float), stream);
    hipMemsetAsync(winner, 0xFF, (size_t)B_ * NPAT_ * sizeof(int), stream);
    winner_kernel<<<(B_ * NP_ + 255) / 256, 256, 0, stream>>>(mask, winner);
    scatter_kernel<<<(B_ * NP_ * OUTD_ + 255) / 256, 256, 0, stream>>>(
        qkv, mask, winner, (float*)d_out);
}

// Round 6
// 2496.974 us; speedup vs baseline: 2.1920x; 1.1043x over previous
//
#include <hip/hip_runtime.h>
#include <hip/hip_bf16.h>
#include <math.h>

// Problem constants
#define B_    8
#define NP_   784
#define ED_   1024
#define D_    512
#define H_    8
#define DH_   64
#define NPAT_ 1568
#define FF_   2048
#define L_    4
#define OUTD_ 1536
#define M_    (B_ * NP_)   // 6272

#define NT_SA 13           // ceil(784/64)
#define NT_CA 25           // ceil(1568/64)

typedef __attribute__((ext_vector_type(8))) short bf16x8;
typedef __attribute__((ext_vector_type(4))) float f32x4;

// split x = hi + lo, both bf16 (truncation: x - hi exact, dropped term ~2^-16 rel)
static __device__ inline void split_bf16(float x, unsigned short& h, unsigned short& l)
{
    unsigned bits = __float_as_uint(x);
    h = (unsigned short)(bits >> 16);
    float r = x - __uint_as_float(bits & 0xFFFF0000u);
    l = (unsigned short)(__float_as_uint(r) >> 16);
}

// ---------------------------------------------------------------------------
// Split-bf16 MFMA GEMM: C[M,N] = A[M,K] @ W[N,K]^T + bias[N], optional GELU.
// (unchanged — validated r2/r5, ~37.6us avg/dispatch, 634 TF MFMA-effective)
// ---------------------------------------------------------------------------
template <int ACT>
__global__ __launch_bounds__(256, 2) void gemm_mfma_kernel(
    const float* __restrict__ A, int lda,
    const float* __restrict__ W, int ldw,
    const float* __restrict__ bias,
    float* __restrict__ C, int ldc,
    int M, int N, int K)
{
    __shared__ short sAh[8 * 512];
    __shared__ short sAl[8 * 512];
    __shared__ short sBh[8 * 512];
    __shared__ short sBl[8 * 512];

    const int t    = threadIdx.x;
    const int lane = t & 63;
    const int wid  = t >> 6;
    const int wr   = wid >> 1;
    const int wc   = wid & 1;
    const int bm   = blockIdx.y * 128;
    const int bn   = blockIdx.x * 128;

    const int srow  = t >> 1;
    const int shalf = t & 1;

    int arow = bm + srow; if (arow >= M) arow = M - 1;
    const float* aptr = A + (size_t)arow * lda + shalf * 16;
    const float* wptr = W + (size_t)(bn + srow) * ldw + shalf * 16;

    const int wbase = (srow >> 4) * 512 + (srow & 15) * 8 + shalf * 256;

    f32x4 acc[4][4];
#pragma unroll
    for (int i = 0; i < 4; i++)
#pragma unroll
        for (int j = 0; j < 4; j++) acc[i][j] = (f32x4)(0.0f);

    for (int k0 = 0; k0 < K; k0 += 32) {
        float4 av[4], wv[4];
#pragma unroll
        for (int q = 0; q < 4; q++) {
            av[q] = *(const float4*)(aptr + k0 + q * 4);
            wv[q] = *(const float4*)(wptr + k0 + q * 4);
        }
        __syncthreads();

        {
            union { short s[16]; bf16x8 v[2]; } ah, al, wh, wl;
#pragma unroll
            for (int q = 0; q < 4; q++) {
                const float* ap = (const float*)&av[q];
                const float* wp = (const float*)&wv[q];
#pragma unroll
                for (int e = 0; e < 4; e++) {
                    int idx = q * 4 + e;
                    unsigned short hh, ll;
                    split_bf16(ap[e], hh, ll);
                    ah.s[idx] = (short)hh; al.s[idx] = (short)ll;
                    split_bf16(wp[e], hh, ll);
                    wh.s[idx] = (short)hh; wl.s[idx] = (short)ll;
                }
            }
            *(bf16x8*)&sAh[wbase]       = ah.v[0];
            *(bf16x8*)&sAh[wbase + 128] = ah.v[1];
            *(bf16x8*)&sAl[wbase]       = al.v[0];
            *(bf16x8*)&sAl[wbase + 128] = al.v[1];
            *(bf16x8*)&sBh[wbase]       = wh.v[0];
            *(bf16x8*)&sBh[wbase + 128] = wh.v[1];
            *(bf16x8*)&sBl[wbase]       = wl.v[0];
            *(bf16x8*)&sBl[wbase + 128] = wl.v[1];
        }
        __syncthreads();

        bf16x8 ahf[4], alf[4], bhf[4], blf[4];
#pragma unroll
        for (int i = 0; i < 4; i++) {
            int sa = (wr * 4 + i) * 512 + lane * 8;
            ahf[i] = *(const bf16x8*)&sAh[sa];
            alf[i] = *(const bf16x8*)&sAl[sa];
        }
#pragma unroll
        for (int j = 0; j < 4; j++) {
            int sb = (wc * 4 + j) * 512 + lane * 8;
            bhf[j] = *(const bf16x8*)&sBh[sb];
            blf[j] = *(const bf16x8*)&sBl[sb];
        }
#pragma unroll
        for (int i = 0; i < 4; i++)
#pragma unroll
            for (int j = 0; j < 4; j++) {
                acc[i][j] = __builtin_amdgcn_mfma_f32_16x16x32_bf16(ahf[i], bhf[j], acc[i][j], 0, 0, 0);
                acc[i][j] = __builtin_amdgcn_mfma_f32_16x16x32_bf16(ahf[i], blf[j], acc[i][j], 0, 0, 0);
                acc[i][j] = __builtin_amdgcn_mfma_f32_16x16x32_bf16(alf[i], bhf[j], acc[i][j], 0, 0, 0);
            }
    }

    float bs[4];
#pragma unroll
    for (int j = 0; j < 4; j++)
        bs[j] = bias[bn + wc * 64 + j * 16 + (lane & 15)];

#pragma unroll
    for (int i = 0; i < 4; i++) {
        int row0 = bm + wr * 64 + i * 16 + ((lane >> 4) << 2);
#pragma unroll
        for (int r = 0; r < 4; r++) {
            int row = row0 + r;
            if (row < M) {
#pragma unroll
                for (int j = 0; j < 4; j++) {
                    int col = bn + wc * 64 + j * 16 + (lane & 15);
                    float v = acc[i][j][r] + bs[j];
                    if (ACT == 1) v = 0.5f * v * (1.0f + erff(v * 0.70710678118654752f));
                    C[(size_t)row * ldc + col] = v;
                }
            }
        }
    }
}

// ---------------------------------------------------------------------------
// K/V pre-conversion: fp32 -> split-bf16 hi/lo planes in MFMA-fragment linear
// order, once per layer (removes per-tile split VALU + transpose conflicts
// from the attention hot loop; round-5 PMC: 2.93e7 conflict cycles/dispatch).
// Output per (bh, tile): [2 planes (hi,lo)][8 subtiles][64 lanes * 8 elems]
//   MODE 0 (K, A-frag):  s=ks*4+f: kv = tile*64 + (s&3)*16 + (m&15),
//                        dh = (s>>2)*32 + (m>>4)*8 + j   (8 contiguous)
//   MODE 1 (V, B-frag):  dh = (s&3)*16 + (m&15),
//                        kv = tile*64 + (s>>2)*32 + (m>>4)*8 + j (8 strided)
// ---------------------------------------------------------------------------
template <int MODE>
__global__ __launch_bounds__(256) void conv_kv_kernel(
    const float* __restrict__ src, int ld, size_t bstride, int rows,
    short* __restrict__ out, int NT)
{
    const int t    = threadIdx.x;
    const int half = blockIdx.x & 1;
    const int tile = blockIdx.x >> 1;
    const int bh   = blockIdx.y;
    const int b    = bh >> 3;          // CA grids have bh < 8 -> b = 0
    const int h    = bh & 7;
    const int s    = half * 4 + (t >> 6);
    const int m    = t & 63;

    float xv[8];
    if (MODE == 0) {
        int kv = tile * 64 + (s & 3) * 16 + (m & 15);
        if (kv >= rows) kv = rows - 1;
        int dh = (s >> 2) * 32 + (m >> 4) * 8;
        const float* p = src + (size_t)b * bstride + (size_t)kv * ld + h * 64 + dh;
        float4 a0 = *(const float4*)p;
        float4 a1 = *(const float4*)(p + 4);
        xv[0] = a0.x; xv[1] = a0.y; xv[2] = a0.z; xv[3] = a0.w;
        xv[4] = a1.x; xv[5] = a1.y; xv[6] = a1.z; xv[7] = a1.w;
    } else {
        int dh  = (s & 3) * 16 + (m & 15);
        int kv0 = tile * 64 + (s >> 2) * 32 + (m >> 4) * 8;
        const float* p = src + (size_t)b * bstride + h * 64 + dh;
#pragma unroll
        for (int j = 0; j < 8; j++) {
            int kv = kv0 + j; if (kv >= rows) kv = rows - 1;
            xv[j] = p[(size_t)kv * ld];
        }
    }
    union { short s_[8]; bf16x8 v; } hi, lo;
#pragma unroll
    for (int e = 0; e < 8; e++) {
        unsigned short hh, ll;
        split_bf16(xv[e], hh, ll);
        hi.s_[e] = (short)hh; lo.s_[e] = (short)ll;
    }
    short* o = out + ((size_t)bh * NT + tile) * 8192 + s * 512 + m * 8;
    *(bf16x8*)o          = hi.v;
    *(bf16x8*)(o + 4096) = lo.v;
}

// ---------------------------------------------------------------------------
// MFMA flash attention v2: K/V read pre-converted (frag-linear), staged with
// contiguous b128 load/ds_write pairs (conflict-floor, zero staging VALU).
// Q pre-scaled by 0.125 (exact pow2 -> S bits unchanged). Compute/P-path
// identical to validated round-5 kernel.
// ---------------------------------------------------------------------------
__global__ __launch_bounds__(256, 3) void attn_mfma2_kernel(
    const float* __restrict__ Q, int ldq, size_t qStride,
    const short* __restrict__ kconv, const short* __restrict__ vconv,
    int bhB,                       // bh = b*bhB + h  (8 for SA, 0 for CA)
    float* __restrict__ O,
    int qLen, int kvLen, int NT)
{
    __shared__ short sK[8192];     // hi [0,4096), lo [4096,8192)
    __shared__ short sV[8192];
    __shared__ short sP[4][2048];  // per wave: hi 1K shorts, lo 1K shorts

    const int t    = threadIdx.x;
    const int lane = t & 63;
    const int wid  = t >> 6;
    const int g    = lane >> 4;
    const int l15  = lane & 15;
    const int qt   = blockIdx.x;
    const int h    = blockIdx.y;
    const int b    = blockIdx.z;
    const int hoff = h * 64;
    const int bh   = b * bhB + h;

    // ---- Q fragments (B-operand layout: col=q=l15, k=dh=g*8+j+32ks) ----
    int qrow = qt * 64 + wid * 16 + l15;
    int qcl  = qrow < qLen ? qrow : qLen - 1;
    const float* qp = Q + (size_t)b * qStride + (size_t)qcl * ldq + hoff + g * 8;
    bf16x8 qh[2], ql[2];
#pragma unroll
    for (int ks = 0; ks < 2; ks++) {
        float4 x0 = *(const float4*)(qp + ks * 32);
        float4 x1 = *(const float4*)(qp + ks * 32 + 4);
        float xv[8] = {x0.x, x0.y, x0.z, x0.w, x1.x, x1.y, x1.z, x1.w};
        union { short s[8]; bf16x8 v; } hi, lo;
#pragma unroll
        for (int e = 0; e < 8; e++) {
            unsigned short hh, ll;
            split_bf16(xv[e] * 0.125f, hh, ll);   // exact pow2 pre-scale
            hi.s[e] = (short)hh; lo.s[e] = (short)ll;
        }
        qh[ks] = hi.v; ql[ks] = lo.v;
    }

    f32x4 o[4];
#pragma unroll
    for (int f = 0; f < 4; f++) o[f] = (f32x4)(0.0f);
    float m = -1e30f, lsum = 0.0f;

    char* const phw = (char*)&sP[wid][0];
    char* const plw = phw + 2048;

    for (int tile = 0; tile < NT; ++tile) {
        const short* kt = kconv + ((size_t)bh * NT + tile) * 8192;
        const short* vt = vconv + ((size_t)bh * NT + tile) * 8192;
        bf16x8 kreg[4], vreg[4];
#pragma unroll
        for (int i = 0; i < 4; i++) {
            kreg[i] = *(const bf16x8*)(kt + i * 2048 + t * 8);
            vreg[i] = *(const bf16x8*)(vt + i * 2048 + t * 8);
        }
        __syncthreads();   // prev tile fully consumed
#pragma unroll
        for (int i = 0; i < 4; i++) {
            *(bf16x8*)&sK[i * 2048 + t * 8] = kreg[i];
            *(bf16x8*)&sV[i * 2048 + t * 8] = vreg[i];
        }
        __syncthreads();   // tile ready

        // ---- QK^T (swapped): S^T[kv][q] ----
        f32x4 s[4];
#pragma unroll
        for (int f = 0; f < 4; f++) s[f] = (f32x4)(0.0f);
#pragma unroll
        for (int f = 0; f < 4; f++)
#pragma unroll
            for (int ks = 0; ks < 2; ks++) {
                int off = (ks * 4 + f) * 512 + lane * 8;
                bf16x8 kh8 = *(const bf16x8*)&sK[off];
                bf16x8 kl8 = *(const bf16x8*)&sK[off + 4096];
                s[f] = __builtin_amdgcn_mfma_f32_16x16x32_bf16(kh8, qh[ks], s[f], 0, 0, 0);
                s[f] = __builtin_amdgcn_mfma_f32_16x16x32_bf16(kh8, ql[ks], s[f], 0, 0, 0);
                s[f] = __builtin_amdgcn_mfma_f32_16x16x32_bf16(kl8, qh[ks], s[f], 0, 0, 0);
            }

        // ---- softmax (per q = l15) ----
        int kv0 = tile * 64;
        float tmax = -1e30f;
#pragma unroll
        for (int f = 0; f < 4; f++)
#pragma unroll
            for (int r = 0; r < 4; r++) {
                float sv = s[f][r];
                int kvg = kv0 + 16 * f + g * 4 + r;
                sv = (kvg < kvLen) ? sv : -1e30f;
                s[f][r] = sv;
                tmax = fmaxf(tmax, sv);
            }
        tmax = fmaxf(tmax, __shfl_xor(tmax, 16));
        tmax = fmaxf(tmax, __shfl_xor(tmax, 32));
        float mnew  = fmaxf(m, tmax);
        float alpha = __expf(m - mnew);
        m = mnew;
        lsum *= alpha;

        // P = exp(S - m), split, pack, write to wave-private swizzled P_lds
#pragma unroll
        for (int f = 0; f < 4; f++) {
            float p0 = __expf(s[f][0] - mnew);
            float p1 = __expf(s[f][1] - mnew);
            float p2 = __expf(s[f][2] - mnew);
            float p3 = __expf(s[f][3] - mnew);
            lsum += (p0 + p1) + (p2 + p3);
            unsigned short h0,h1,h2,h3, l0,l1,l2,l3;
            split_bf16(p0, h0, l0); split_bf16(p1, h1, l1);
            split_bf16(p2, h2, l2); split_bf16(p3, h3, l3);
            uint2 uh, ul;
            uh.x = (unsigned)h0 | ((unsigned)h1 << 16);
            uh.y = (unsigned)h2 | ((unsigned)h3 << 16);
            ul.x = (unsigned)l0 | ((unsigned)l1 << 16);
            ul.y = (unsigned)l2 | ((unsigned)l3 << 16);
            int wa = (l15 * 128 + f * 32 + g * 8) ^ ((l15 & 7) << 4);
            *(uint2*)(phw + wa) = uh;
            *(uint2*)(plw + wa) = ul;
        }

        // rescale O by alpha of its q rows (q = g*4+r lives at lane g*4+r)
        {
            float a0 = __shfl(alpha, g * 4 + 0);
            float a1 = __shfl(alpha, g * 4 + 1);
            float a2 = __shfl(alpha, g * 4 + 2);
            float a3 = __shfl(alpha, g * 4 + 3);
#pragma unroll
            for (int f = 0; f < 4; f++) {
                o[f][0] *= a0; o[f][1] *= a1; o[f][2] *= a2; o[f][3] *= a3;
            }
        }

        // ---- PV: O += P * V ----
#pragma unroll
        for (int ks = 0; ks < 2; ks++) {
            int pa = (l15 * 128 + ks * 64 + g * 16) ^ ((l15 & 7) << 4);
            bf16x8 p_h = *(const bf16x8*)(phw + pa);
            bf16x8 p_l = *(const bf16x8*)(plw + pa);
#pragma unroll
            for (int f = 0; f < 4; f++) {
                int off = (ks * 4 + f) * 512 + lane * 8;
                bf16x8 vh8 = *(const bf16x8*)&sV[off];
                bf16x8 vl8 = *(const bf16x8*)&sV[off + 4096];
                o[f] = __builtin_amdgcn_mfma_f32_16x16x32_bf16(p_h, vh8, o[f], 0, 0, 0);
                o[f] = __builtin_amdgcn_mfma_f32_16x16x32_bf16(p_h, vl8, o[f], 0, 0, 0);
                o[f] = __builtin_amdgcn_mfma_f32_16x16x32_bf16(p_l, vh8, o[f], 0, 0, 0);
            }
        }
    }

    // ---- epilogue ----
    lsum += __shfl_xor(lsum, 16);
    lsum += __shfl_xor(lsum, 32);
    float linv = 1.0f / lsum;
    float lr0 = __shfl(linv, g * 4 + 0);
    float lr1 = __shfl(linv, g * 4 + 1);
    float lr2 = __shfl(linv, g * 4 + 2);
    float lr3 = __shfl(linv, g * 4 + 3);
    float lr[4] = {lr0, lr1, lr2, lr3};

    int row0 = qt * 64 + wid * 16 + g * 4;
#pragma unroll
    for (int r = 0; r < 4; r++) {
        int row = row0 + r;
        if (row < qLen) {
            float* op = O + ((size_t)b * qLen + row) * 512 + hoff + l15;
#pragma unroll
            for (int f = 0; f < 4; f++)
                op[f * 16] = o[f][r] * lr[r];
        }
    }
}

// ---------------------------------------------------------------------------
// LayerNorm over D=512: out = LN(a + res) * w + b. One wave per row.
// ---------------------------------------------------------------------------
__global__ __launch_bounds__(256) void ln_kernel(
    const float* __restrict__ a, const float* __restrict__ res,
    const float* __restrict__ w, const float* __restrict__ bb,
    float* __restrict__ out, int M)
{
    const int wid  = threadIdx.x >> 6;
    const int lane = threadIdx.x & 63;
    const int row  = blockIdx.x * 4 + wid;
    if (row >= M) return;

    const float* ap = a + (size_t)row * 512 + lane * 8;
    float4 x0 = *(const float4*)ap;
    float4 x1 = *(const float4*)(ap + 4);
    float v[8] = {x0.x, x0.y, x0.z, x0.w, x1.x, x1.y, x1.z, x1.w};
    if (res) {
        const float* rp = res + (size_t)row * 512 + lane * 8;
        float4 r0 = *(const float4*)rp;
        float4 r1 = *(const float4*)(rp + 4);
        v[0] += r0.x; v[1] += r0.y; v[2] += r0.z; v[3] += r0.w;
        v[4] += r1.x; v[5] += r1.y; v[6] += r1.z; v[7] += r1.w;
    }
    float sum = 0.f, sq = 0.f;
#pragma unroll
    for (int j = 0; j < 8; j++) { sum += v[j]; sq = fmaf(v[j], v[j], sq); }
#pragma unroll
    for (int off = 1; off < 64; off <<= 1) {
        sum += __shfl_xor(sum, off);
        sq  += __shfl_xor(sq, off);
    }
    float mean = sum * (1.0f / 512.0f);
    float var  = sq * (1.0f / 512.0f) - mean * mean;
    float rstd = 1.0f / sqrtf(var + 1e-5f);

    const float* wp = w + lane * 8;
    const float* bp = bb + lane * 8;
    float ov[8];
#pragma unroll
    for (int j = 0; j < 8; j++) ov[j] = (v[j] - mean) * rstd * wp[j] + bp[j];
    float* op = out + (size_t)row * 512 + lane * 8;
    *(float4*)op       = make_float4(ov[0], ov[1], ov[2], ov[3]);
    *(float4*)(op + 4) = make_float4(ov[4], ov[5], ov[6], ov[7]);
}

// ---------------------------------------------------------------------------
// Sin/cos positional embedding.
// ---------------------------------------------------------------------------
__global__ __launch_bounds__(256) void posembed_kernel(float* __restrict__ mem)
{
    int idx = blockIdx.x * 256 + threadIdx.x;
    if (idx >= NPAT_ * 256) return;
    int pos = idx >> 8;
    int i   = idx & 255;
    float div = expf((float)(2 * i) * (-9.21034037197618f / 512.0f));
    float ang = (float)pos * div;
    mem[(size_t)pos * 512 + 2 * i]     = sinf(ang);
    mem[(size_t)pos * 512 + 2 * i + 1] = cosf(ang);
}

// ---------------------------------------------------------------------------
// Scatter: winner pass (last p wins per (b, slot)) then patch writes.
// ---------------------------------------------------------------------------
__global__ __launch_bounds__(256) void winner_kernel(
    const int* __restrict__ mask, int* __restrict__ winner)
{
    int idx = blockIdx.x * 256 + threadIdx.x;
    if (idx >= B_ * NP_) return;
    int b = idx / NP_;
    atomicMax(&winner[b * NPAT_ + mask[idx]], idx % NP_);
}

__global__ __launch_bounds__(256) void scatter_kernel(
    const float* __restrict__ pred, const int* __restrict__ mask,
    const int* __restrict__ winner, float* __restrict__ out)
{
    int idx = blockIdx.x * 256 + threadIdx.x;
    if (idx >= B_ * NP_ * OUTD_) return;
    int e  = idx % OUTD_;
    int bp = idx / OUTD_;
    int p  = bp % NP_;
    int b  = bp / NP_;
    int mv = mask[b * NP_ + p];
    if (winner[b * NPAT_ + mv] != p) return;

    int f  = e / 768;
    int rm = e % 768;
    int c  = rm / 256;
    int r2 = rm % 256;
    int ph = r2 / 16;
    int pw = r2 % 16;
    int tt = mv / 196;
    int ss = mv % 196;
    int hi = ss / 14;
    int wi = ss % 14;

    size_t dst = ((size_t)((b * 16 + tt * 2 + f) * 3 + c)) * (224 * 224)
               + (size_t)(hi * 16 + ph) * 224 + (wi * 16 + pw);
    out[dst] = pred[(size_t)bp * OUTD_ + e];
}

// ---------------------------------------------------------------------------
extern "C" void kernel_launch(void* const* d_in, const int* in_sizes, int n_in,
                              void* d_out, int out_size, void* d_ws, size_t ws_size,
                              hipStream_t stream)
{
    const float* z       = (const float*)d_in[0];
    const int*   mask    = (const int*)d_in[1];
    const float* embed_w = (const float*)d_in[2];
    const float* embed_b = (const float*)d_in[3];
    const float* sa_qkv_w = (const float*)d_in[4];
    const float* sa_qkv_b = (const float*)d_in[5];
    const float* sa_out_w = (const float*)d_in[6];
    const float* sa_out_b = (const float*)d_in[7];
    const float* ca_qkv_w = (const float*)d_in[8];
    const float* ca_qkv_b = (const float*)d_in[9];
    const float* ca_out_w = (const float*)d_in[10];
    const float* ca_out_b = (const float*)d_in[11];
    const float* ff1_w = (const float*)d_in[12];
    const float* ff1_b = (const float*)d_in[13];
    const float* ff2_w = (const float*)d_in[14];
    const float* ff2_b = (const float*)d_in[15];
    const float* ln1_w = (const float*)d_in[16];
    const float* ln1_b = (const float*)d_in[17];
    const float* ln2_w = (const float*)d_in[18];
    const float* ln2_b = (const float*)d_in[19];
    const float* ln3_w = (const float*)d_in[20];
    const float* ln3_b = (const float*)d_in[21];
    const float* norm_w = (const float*)d_in[22];
    const float* norm_b = (const float*)d_in[23];
    const float* pred_w = (const float*)d_in[24];
    const float* pred_b = (const float*)d_in[25];

    float* ws  = (float*)d_ws;
    float* x   = ws;                          // [6272, 512]
    float* y   = x   + (size_t)M_ * 512;      // [6272, 2048] (gemm out / conv alias)
    float* qkv = y   + (size_t)M_ * 2048;     // [6272, 1536]
    float* att = qkv + (size_t)M_ * 1536;     // [6272, 512]
    float* mem = att + (size_t)M_ * 512;      // [1568, 512]
    float* ckv = mem + (size_t)NPAT_ * 512;   // [1568, 1024]
    int* winner = (int*)(ckv + (size_t)NPAT_ * 1024);   // [8, 1568]

    // conv buffers alias y (y is dead between qkv-GEMM and out-GEMM of each attn)
    short* kconvSA = (short*)y;                                   // 64*13*8192 shorts
    short* vconvSA = kconvSA + (size_t)64 * NT_SA * 8192;
    short* kconvCA = vconvSA + (size_t)64 * NT_SA * 8192;         // 8*25*8192
    short* vconvCA = kconvCA + (size_t)8 * NT_CA * 8192;

    posembed_kernel<<<NPAT_, 256, 0, stream>>>(mem);

    gemm_mfma_kernel<0><<<dim3(512 / 128, M_ / 128), 256, 0, stream>>>(
        z, ED_, embed_w, ED_, embed_b, x, 512, M_, 512, ED_);

    for (int l = 0; l < L_; l++) {
        const float* saw = sa_qkv_w + (size_t)l * 1536 * 512;
        const float* sab = sa_qkv_b + (size_t)l * 1536;
        const float* sow = sa_out_w + (size_t)l * 512 * 512;
        const float* sob = sa_out_b + (size_t)l * 512;
        const float* caw = ca_qkv_w + (size_t)l * 1536 * 512;
        const float* cab = ca_qkv_b + (size_t)l * 1536;
        const float* cow = ca_out_w + (size_t)l * 512 * 512;
        const float* cob = ca_out_b + (size_t)l * 512;
        const float* f1w = ff1_w + (size_t)l * 2048 * 512;
        const float* f1b = ff1_b + (size_t)l * 2048;
        const float* f2w = ff2_w + (size_t)l * 512 * 2048;
        const float* f2b = ff2_b + (size_t)l * 512;

        // ---- self-attention ----
        gemm_mfma_kernel<0><<<dim3(1536 / 128, M_ / 128), 256, 0, stream>>>(
            x, 512, saw, 512, sab, qkv, 1536, M_, 1536, 512);
        conv_kv_kernel<0><<<dim3(NT_SA * 2, 64), 256, 0, stream>>>(
            qkv + 512, 1536, (size_t)NP_ * 1536, NP_, kconvSA, NT_SA);
        conv_kv_kernel<1><<<dim3(NT_SA * 2, 64), 256, 0, stream>>>(
            qkv + 1024, 1536, (size_t)NP_ * 1536, NP_, vconvSA, NT_SA);
        attn_mfma2_kernel<<<dim3(13, H_, B_), 256, 0, stream>>>(
            qkv, 1536, (size_t)NP_ * 1536, kconvSA, vconvSA, 8,
            att, NP_, NP_, NT_SA);
        gemm_mfma_kernel<0><<<dim3(512 / 128, M_ / 128), 256, 0, stream>>>(
            att, 512, sow, 512, sob, y, 512, M_, 512, 512);
        ln_kernel<<<(M_ + 3) / 4, 256, 0, stream>>>(
            y, x, ln1_w + l * 512, ln1_b + l * 512, x, M_);

        // ---- cross-attention (K/V batch-shared: computed once over NPAT) ----
        gemm_mfma_kernel<0><<<dim3(512 / 128, M_ / 128), 256, 0, stream>>>(
            x, 512, caw, 512, cab, qkv, 512, M_, 512, 512);
        gemm_mfma_kernel<0><<<dim3(1024 / 128, (NPAT_ + 127) / 128), 256, 0, stream>>>(
            mem, 512, caw + 512 * 512, 512, cab + 512, ckv, 1024, NPAT_, 1024, 512);
        conv_kv_kernel<0><<<dim3(NT_CA * 2, 8), 256, 0, stream>>>(
            ckv, 1024, (size_t)0, NPAT_, kconvCA, NT_CA);
        conv_kv_kernel<1><<<dim3(NT_CA * 2, 8), 256, 0, stream>>>(
            ckv + 512, 1024, (size_t)0, NPAT_, vconvCA, NT_CA);
        attn_mfma2_kernel<<<dim3(13, H_, B_), 256, 0, stream>>>(
            qkv, 512, (size_t)NP_ * 512, kconvCA, vconvCA, 0,
            att, NP_, NPAT_, NT_CA);
        gemm_mfma_kernel<0><<<dim3(512 / 128, M_ / 128), 256, 0, stream>>>(
            att, 512, cow, 512, cob, y, 512, M_, 512, 512);
        ln_kernel<<<(M_ + 3) / 4, 256, 0, stream>>>(
            y, x, ln2_w + l * 512, ln2_b + l * 512, x, M_);

        // ---- feed-forward ----
        gemm_mfma_kernel<1><<<dim3(2048 / 128, M_ / 128), 256, 0, stream>>>(
            x, 512, f1w, 512, f1b, y, 2048, M_, 2048, 512);
        gemm_mfma_kernel<0><<<dim3(512 / 128, M_ / 128), 256, 0, stream>>>(
            y, 2048, f2w, 2048, f2b, att, 512, M_, 512, 2048);
        ln_kernel<<<(M_ + 3) / 4, 256, 0, stream>>>(
            att, x, ln3_w + l * 512, ln3_b + l * 512, x, M_);
    }

    ln_kernel<<<(M_ + 3) / 4, 256, 0, stream>>>(x, nullptr, norm_w, norm_b, x, M_);
    gemm_mfma_kernel<0><<<dim3(1536 / 128, M_ / 128), 256, 0, stream>>>(
        x, 512, pred_w, 512, pred_b, qkv, 1536, M_, 1536, 512);

    hipMemsetAsync(d_out, 0, (size_t)out_size * sizeof(float), stream);
    hipMemsetAsync(winner, 0xFF, (size_t)B_ * NPAT_ * sizeof(int), stream);
    winner_kernel<<<(B_ * NP_ + 255) / 256, 256, 0, stream>>>(mask, winner);
    scatter_kernel<<<(B_ * NP_ * OUTD_ + 255) / 256, 256, 0, stream>>>(
        qkv, mask, winner, (float*)d_out);
}

// Round 7
// 2128.845 us; speedup vs baseline: 2.5711x; 1.1729x over previous
//
#include <hip/hip_runtime.h>
#include <hip/hip_bf16.h>
#include <math.h>

// Problem constants
#define B_    8
#define NP_   784
#define ED_   1024
#define D_    512
#define H_    8
#define DH_   64
#define NPAT_ 1568
#define FF_   2048
#define L_    4
#define OUTD_ 1536
#define M_    (B_ * NP_)   // 6272

#define NT_SA 13           // ceil(784/64)
#define NT_CA 25           // ceil(1568/64)

typedef __attribute__((ext_vector_type(8))) short bf16x8;
typedef __attribute__((ext_vector_type(4))) float f32x4;

// split x = hi + lo, both bf16 (truncation: x - hi exact, dropped term ~2^-16 rel)
static __device__ inline void split_bf16(float x, unsigned short& h, unsigned short& l)
{
    unsigned bits = __float_as_uint(x);
    h = (unsigned short)(bits >> 16);
    float r = x - __uint_as_float(bits & 0xFFFF0000u);
    l = (unsigned short)(__float_as_uint(r) >> 16);
}

// ---------------------------------------------------------------------------
// Weight pre-split: W[N,K] fp32 -> hi/lo bf16 planes in B-frag-linear order.
// Layout: subtile gs = kb*(N/16)+ns holds 1024 shorts: [0,512)=hi, [512,1024)=lo,
// elem m*8+e = W[ns*16+(m&15)][kb*32+(m>>4)*8+e].  One dispatch per weight
// tensor (blockIdx.y = layer), 4 subtiles per 256-thr block.
// ---------------------------------------------------------------------------
__global__ __launch_bounds__(256) void conv_w_kernel(
    const float* __restrict__ src, size_t lss, int N, int K,
    short* __restrict__ dst, size_t lsd)
{
    const int t  = threadIdx.x;
    const int l  = blockIdx.y;
    const int gs = blockIdx.x * 4 + (t >> 6);
    const int m  = t & 63;
    const int NB16 = N >> 4;
    const int kb = gs / NB16;
    const int ns = gs % NB16;

    const float* p = src + (size_t)l * lss + (size_t)(ns * 16 + (m & 15)) * K
                   + kb * 32 + (m >> 4) * 8;
    float4 a0 = *(const float4*)p;
    float4 a1 = *(const float4*)(p + 4);
    float xv[8] = {a0.x, a0.y, a0.z, a0.w, a1.x, a1.y, a1.z, a1.w};
    union { short s_[8]; bf16x8 v; } hi, lo;
#pragma unroll
    for (int e = 0; e < 8; e++) {
        unsigned short hh, ll;
        split_bf16(xv[e], hh, ll);
        hi.s_[e] = (short)hh; lo.s_[e] = (short)ll;
    }
    short* o = dst + (size_t)l * lsd + (size_t)gs * 1024 + m * 8;
    *(bf16x8*)o         = hi.v;
    *(bf16x8*)(o + 512) = lo.v;
}

// ---------------------------------------------------------------------------
// Split-bf16 MFMA GEMM: C[M,N] = A[M,K] @ W[N,K]^T + bias, optional GELU.
// PW=1: B read from pre-split frag-linear planes (pure b128 copy staging).
// Split-K: grid.z = K/KC chunks; chunk z covers k in [z*KC,(z+1)*KC), writes
// C + z*cstride; bias folded into chunk-0 accumulator init.
// ---------------------------------------------------------------------------
template <int ACT, int PW>
__global__ __launch_bounds__(256, 2) void gemm_mfma_kernel(
    const float* __restrict__ A, int lda,
    const float* __restrict__ W, int ldw,
    const short* __restrict__ wsp, int NB16, int cOff,
    const float* __restrict__ bias,
    float* __restrict__ C, int ldc, size_t cstride,
    int M, int N, int K, int KC)
{
    __shared__ short sAh[8 * 512];
    __shared__ short sAl[8 * 512];
    __shared__ short sBh[8 * 512];
    __shared__ short sBl[8 * 512];

    const int t    = threadIdx.x;
    const int lane = t & 63;
    const int wid  = t >> 6;
    const int wr   = wid >> 1;
    const int wc   = wid & 1;
    const int bm   = blockIdx.y * 128;
    const int bn   = blockIdx.x * 128;
    const int kBeg = blockIdx.z * KC;
    C += (size_t)blockIdx.z * cstride;

    const int srow  = t >> 1;
    const int shalf = t & 1;

    int arow = bm + srow; if (arow >= M) arow = M - 1;
    const float* aptr = A + (size_t)arow * lda + shalf * 16;
    const float* wptr = (PW == 0) ? (W + (size_t)(bn + srow) * ldw + shalf * 16) : nullptr;

    const int wbase = (srow >> 4) * 512 + (srow & 15) * 8 + shalf * 256;

    f32x4 acc[4][4];
    {
        const int col = bn + wc * 64 + (lane & 15);
#pragma unroll
        for (int j = 0; j < 4; j++) {
            float bv = (blockIdx.z == 0) ? bias[col + j * 16] : 0.0f;
            for (int i = 0; i < 4; i++) acc[i][j] = (f32x4)(bv);
        }
    }

    for (int k0 = kBeg; k0 < kBeg + KC; k0 += 32) {
        float4 av[4];
#pragma unroll
        for (int q = 0; q < 4; q++) av[q] = *(const float4*)(aptr + k0 + q * 4);

        float4 wv[4];
        bf16x8 bh0, bh1, bl0, bl1;
        if constexpr (PW == 0) {
#pragma unroll
            for (int q = 0; q < 4; q++) wv[q] = *(const float4*)(wptr + k0 + q * 4);
        } else {
            const short* gb = wsp + ((size_t)(k0 >> 5) * NB16 + (bn >> 4) + cOff) * 1024
                            + (t >> 5) * 1024 + (t & 31) * 16;
            bh0 = *(const bf16x8*)gb;
            bh1 = *(const bf16x8*)(gb + 8);
            bl0 = *(const bf16x8*)(gb + 512);
            bl1 = *(const bf16x8*)(gb + 520);
        }
        __syncthreads();   // previous tile fully consumed

        {
            union { short s[16]; bf16x8 v[2]; } ah, al;
#pragma unroll
            for (int q = 0; q < 4; q++) {
                const float* ap = (const float*)&av[q];
#pragma unroll
                for (int e = 0; e < 4; e++) {
                    unsigned short hh, ll;
                    split_bf16(ap[e], hh, ll);
                    ah.s[q * 4 + e] = (short)hh; al.s[q * 4 + e] = (short)ll;
                }
            }
            *(bf16x8*)&sAh[wbase]       = ah.v[0];
            *(bf16x8*)&sAh[wbase + 128] = ah.v[1];
            *(bf16x8*)&sAl[wbase]       = al.v[0];
            *(bf16x8*)&sAl[wbase + 128] = al.v[1];
        }
        if constexpr (PW == 0) {
            union { short s[16]; bf16x8 v[2]; } wh, wl;
#pragma unroll
            for (int q = 0; q < 4; q++) {
                const float* wp = (const float*)&wv[q];
#pragma unroll
                for (int e = 0; e < 4; e++) {
                    unsigned short hh, ll;
                    split_bf16(wp[e], hh, ll);
                    wh.s[q * 4 + e] = (short)hh; wl.s[q * 4 + e] = (short)ll;
                }
            }
            *(bf16x8*)&sBh[wbase]       = wh.v[0];
            *(bf16x8*)&sBh[wbase + 128] = wh.v[1];
            *(bf16x8*)&sBl[wbase]       = wl.v[0];
            *(bf16x8*)&sBl[wbase + 128] = wl.v[1];
        } else {
            *(bf16x8*)&sBh[t * 16]     = bh0;
            *(bf16x8*)&sBh[t * 16 + 8] = bh1;
            *(bf16x8*)&sBl[t * 16]     = bl0;
            *(bf16x8*)&sBl[t * 16 + 8] = bl1;
        }
        __syncthreads();

        bf16x8 ahf[4], alf[4], bhf[4], blf[4];
#pragma unroll
        for (int i = 0; i < 4; i++) {
            int sa = (wr * 4 + i) * 512 + lane * 8;
            ahf[i] = *(const bf16x8*)&sAh[sa];
            alf[i] = *(const bf16x8*)&sAl[sa];
        }
#pragma unroll
        for (int j = 0; j < 4; j++) {
            int sb = (wc * 4 + j) * 512 + lane * 8;
            bhf[j] = *(const bf16x8*)&sBh[sb];
            blf[j] = *(const bf16x8*)&sBl[sb];
        }
#pragma unroll
        for (int i = 0; i < 4; i++)
#pragma unroll
            for (int j = 0; j < 4; j++) {
                acc[i][j] = __builtin_amdgcn_mfma_f32_16x16x32_bf16(ahf[i], bhf[j], acc[i][j], 0, 0, 0);
                acc[i][j] = __builtin_amdgcn_mfma_f32_16x16x32_bf16(ahf[i], blf[j], acc[i][j], 0, 0, 0);
                acc[i][j] = __builtin_amdgcn_mfma_f32_16x16x32_bf16(alf[i], bhf[j], acc[i][j], 0, 0, 0);
            }
    }

#pragma unroll
    for (int i = 0; i < 4; i++) {
        int row0 = bm + wr * 64 + i * 16 + ((lane >> 4) << 2);
#pragma unroll
        for (int r = 0; r < 4; r++) {
            int row = row0 + r;
            if (row < M) {
#pragma unroll
                for (int j = 0; j < 4; j++) {
                    int col = bn + wc * 64 + j * 16 + (lane & 15);
                    float v = acc[i][j][r];
                    if (ACT == 1) v = 0.5f * v * (1.0f + erff(v * 0.70710678118654752f));
                    C[(size_t)row * ldc + col] = v;
                }
            }
        }
    }
}

static inline void launch_gemm(bool pw, bool act, dim3 grid, hipStream_t st,
    const float* A, int lda, const float* W, int ldw,
    const short* wsp, int NB16, int cOff, const float* bias,
    float* C, int ldc, size_t cstride, int M, int N, int K, int KC)
{
    if (pw) {
        if (act) gemm_mfma_kernel<1,1><<<grid,256,0,st>>>(A,lda,W,ldw,wsp,NB16,cOff,bias,C,ldc,cstride,M,N,K,KC);
        else     gemm_mfma_kernel<0,1><<<grid,256,0,st>>>(A,lda,W,ldw,wsp,NB16,cOff,bias,C,ldc,cstride,M,N,K,KC);
    } else {
        if (act) gemm_mfma_kernel<1,0><<<grid,256,0,st>>>(A,lda,W,ldw,wsp,NB16,cOff,bias,C,ldc,cstride,M,N,K,KC);
        else     gemm_mfma_kernel<0,0><<<grid,256,0,st>>>(A,lda,W,ldw,wsp,NB16,cOff,bias,C,ldc,cstride,M,N,K,KC);
    }
}

// ---------------------------------------------------------------------------
// K/V pre-conversion for attention (unchanged, validated round 6).
// ---------------------------------------------------------------------------
template <int MODE>
__global__ __launch_bounds__(256) void conv_kv_kernel(
    const float* __restrict__ src, int ld, size_t bstride, int rows,
    short* __restrict__ out, int NT)
{
    const int t    = threadIdx.x;
    const int half = blockIdx.x & 1;
    const int tile = blockIdx.x >> 1;
    const int bh   = blockIdx.y;
    const int b    = bh >> 3;
    const int h    = bh & 7;
    const int s    = half * 4 + (t >> 6);
    const int m    = t & 63;

    float xv[8];
    if (MODE == 0) {
        int kv = tile * 64 + (s & 3) * 16 + (m & 15);
        if (kv >= rows) kv = rows - 1;
        int dh = (s >> 2) * 32 + (m >> 4) * 8;
        const float* p = src + (size_t)b * bstride + (size_t)kv * ld + h * 64 + dh;
        float4 a0 = *(const float4*)p;
        float4 a1 = *(const float4*)(p + 4);
        xv[0] = a0.x; xv[1] = a0.y; xv[2] = a0.z; xv[3] = a0.w;
        xv[4] = a1.x; xv[5] = a1.y; xv[6] = a1.z; xv[7] = a1.w;
    } else {
        int dh  = (s & 3) * 16 + (m & 15);
        int kv0 = tile * 64 + (s >> 2) * 32 + (m >> 4) * 8;
        const float* p = src + (size_t)b * bstride + h * 64 + dh;
#pragma unroll
        for (int j = 0; j < 8; j++) {
            int kv = kv0 + j; if (kv >= rows) kv = rows - 1;
            xv[j] = p[(size_t)kv * ld];
        }
    }
    union { short s_[8]; bf16x8 v; } hi, lo;
#pragma unroll
    for (int e = 0; e < 8; e++) {
        unsigned short hh, ll;
        split_bf16(xv[e], hh, ll);
        hi.s_[e] = (short)hh; lo.s_[e] = (short)ll;
    }
    short* o = out + ((size_t)bh * NT + tile) * 8192 + s * 512 + m * 8;
    *(bf16x8*)o          = hi.v;
    *(bf16x8*)(o + 4096) = lo.v;
}

// ---------------------------------------------------------------------------
// MFMA flash attention v2 (unchanged, validated round 6).
// ---------------------------------------------------------------------------
__global__ __launch_bounds__(256, 3) void attn_mfma2_kernel(
    const float* __restrict__ Q, int ldq, size_t qStride,
    const short* __restrict__ kconv, const short* __restrict__ vconv,
    int bhB,
    float* __restrict__ O,
    int qLen, int kvLen, int NT)
{
    __shared__ short sK[8192];
    __shared__ short sV[8192];
    __shared__ short sP[4][2048];

    const int t    = threadIdx.x;
    const int lane = t & 63;
    const int wid  = t >> 6;
    const int g    = lane >> 4;
    const int l15  = lane & 15;
    const int qt   = blockIdx.x;
    const int h    = blockIdx.y;
    const int b    = blockIdx.z;
    const int hoff = h * 64;
    const int bh   = b * bhB + h;

    int qrow = qt * 64 + wid * 16 + l15;
    int qcl  = qrow < qLen ? qrow : qLen - 1;
    const float* qp = Q + (size_t)b * qStride + (size_t)qcl * ldq + hoff + g * 8;
    bf16x8 qh[2], ql[2];
#pragma unroll
    for (int ks = 0; ks < 2; ks++) {
        float4 x0 = *(const float4*)(qp + ks * 32);
        float4 x1 = *(const float4*)(qp + ks * 32 + 4);
        float xv[8] = {x0.x, x0.y, x0.z, x0.w, x1.x, x1.y, x1.z, x1.w};
        union { short s[8]; bf16x8 v; } hi, lo;
#pragma unroll
        for (int e = 0; e < 8; e++) {
            unsigned short hh, ll;
            split_bf16(xv[e] * 0.125f, hh, ll);
            hi.s[e] = (short)hh; lo.s[e] = (short)ll;
        }
        qh[ks] = hi.v; ql[ks] = lo.v;
    }

    f32x4 o[4];
#pragma unroll
    for (int f = 0; f < 4; f++) o[f] = (f32x4)(0.0f);
    float m = -1e30f, lsum = 0.0f;

    char* const phw = (char*)&sP[wid][0];
    char* const plw = phw + 2048;

    for (int tile = 0; tile < NT; ++tile) {
        const short* kt = kconv + ((size_t)bh * NT + tile) * 8192;
        const short* vt = vconv + ((size_t)bh * NT + tile) * 8192;
        bf16x8 kreg[4], vreg[4];
#pragma unroll
        for (int i = 0; i < 4; i++) {
            kreg[i] = *(const bf16x8*)(kt + i * 2048 + t * 8);
            vreg[i] = *(const bf16x8*)(vt + i * 2048 + t * 8);
        }
        __syncthreads();
#pragma unroll
        for (int i = 0; i < 4; i++) {
            *(bf16x8*)&sK[i * 2048 + t * 8] = kreg[i];
            *(bf16x8*)&sV[i * 2048 + t * 8] = vreg[i];
        }
        __syncthreads();

        f32x4 s[4];
#pragma unroll
        for (int f = 0; f < 4; f++) s[f] = (f32x4)(0.0f);
#pragma unroll
        for (int f = 0; f < 4; f++)
#pragma unroll
            for (int ks = 0; ks < 2; ks++) {
                int off = (ks * 4 + f) * 512 + lane * 8;
                bf16x8 kh8 = *(const bf16x8*)&sK[off];
                bf16x8 kl8 = *(const bf16x8*)&sK[off + 4096];
                s[f] = __builtin_amdgcn_mfma_f32_16x16x32_bf16(kh8, qh[ks], s[f], 0, 0, 0);
                s[f] = __builtin_amdgcn_mfma_f32_16x16x32_bf16(kh8, ql[ks], s[f], 0, 0, 0);
                s[f] = __builtin_amdgcn_mfma_f32_16x16x32_bf16(kl8, qh[ks], s[f], 0, 0, 0);
            }

        int kv0 = tile * 64;
        float tmax = -1e30f;
#pragma unroll
        for (int f = 0; f < 4; f++)
#pragma unroll
            for (int r = 0; r < 4; r++) {
                float sv = s[f][r];
                int kvg = kv0 + 16 * f + g * 4 + r;
                sv = (kvg < kvLen) ? sv : -1e30f;
                s[f][r] = sv;
                tmax = fmaxf(tmax, sv);
            }
        tmax = fmaxf(tmax, __shfl_xor(tmax, 16));
        tmax = fmaxf(tmax, __shfl_xor(tmax, 32));
        float mnew  = fmaxf(m, tmax);
        float alpha = __expf(m - mnew);
        m = mnew;
        lsum *= alpha;

#pragma unroll
        for (int f = 0; f < 4; f++) {
            float p0 = __expf(s[f][0] - mnew);
            float p1 = __expf(s[f][1] - mnew);
            float p2 = __expf(s[f][2] - mnew);
            float p3 = __expf(s[f][3] - mnew);
            lsum += (p0 + p1) + (p2 + p3);
            unsigned short h0,h1,h2,h3, l0,l1,l2,l3;
            split_bf16(p0, h0, l0); split_bf16(p1, h1, l1);
            split_bf16(p2, h2, l2); split_bf16(p3, h3, l3);
            uint2 uh, ul;
            uh.x = (unsigned)h0 | ((unsigned)h1 << 16);
            uh.y = (unsigned)h2 | ((unsigned)h3 << 16);
            ul.x = (unsigned)l0 | ((unsigned)l1 << 16);
            ul.y = (unsigned)l2 | ((unsigned)l3 << 16);
            int wa = (l15 * 128 + f * 32 + g * 8) ^ ((l15 & 7) << 4);
            *(uint2*)(phw + wa) = uh;
            *(uint2*)(plw + wa) = ul;
        }

        {
            float a0 = __shfl(alpha, g * 4 + 0);
            float a1 = __shfl(alpha, g * 4 + 1);
            float a2 = __shfl(alpha, g * 4 + 2);
            float a3 = __shfl(alpha, g * 4 + 3);
#pragma unroll
            for (int f = 0; f < 4; f++) {
                o[f][0] *= a0; o[f][1] *= a1; o[f][2] *= a2; o[f][3] *= a3;
            }
        }

#pragma unroll
        for (int ks = 0; ks < 2; ks++) {
            int pa = (l15 * 128 + ks * 64 + g * 16) ^ ((l15 & 7) << 4);
            bf16x8 p_h = *(const bf16x8*)(phw + pa);
            bf16x8 p_l = *(const bf16x8*)(plw + pa);
#pragma unroll
            for (int f = 0; f < 4; f++) {
                int off = (ks * 4 + f) * 512 + lane * 8;
                bf16x8 vh8 = *(const bf16x8*)&sV[off];
                bf16x8 vl8 = *(const bf16x8*)&sV[off + 4096];
                o[f] = __builtin_amdgcn_mfma_f32_16x16x32_bf16(p_h, vh8, o[f], 0, 0, 0);
                o[f] = __builtin_amdgcn_mfma_f32_16x16x32_bf16(p_h, vl8, o[f], 0, 0, 0);
                o[f] = __builtin_amdgcn_mfma_f32_16x16x32_bf16(p_l, vh8, o[f], 0, 0, 0);
            }
        }
    }

    lsum += __shfl_xor(lsum, 16);
    lsum += __shfl_xor(lsum, 32);
    float linv = 1.0f / lsum;
    float lr0 = __shfl(linv, g * 4 + 0);
    float lr1 = __shfl(linv, g * 4 + 1);
    float lr2 = __shfl(linv, g * 4 + 2);
    float lr3 = __shfl(linv, g * 4 + 3);
    float lr[4] = {lr0, lr1, lr2, lr3};

    int row0 = qt * 64 + wid * 16 + g * 4;
#pragma unroll
    for (int r = 0; r < 4; r++) {
        int row = row0 + r;
        if (row < qLen) {
            float* op = O + ((size_t)b * qLen + row) * 512 + hoff + l15;
#pragma unroll
            for (int f = 0; f < 4; f++)
                op[f * 16] = o[f][r] * lr[r];
        }
    }
}

// ---------------------------------------------------------------------------
// LayerNorm over D=512, with fused split-K reduction: in = sum of nParts
// partial buffers (+ res). One wave per row.
// ---------------------------------------------------------------------------
__global__ __launch_bounds__(256) void ln_kernel(
    const float* __restrict__ a, int nParts, size_t pstride,
    const float* __restrict__ res,
    const float* __restrict__ w, const float* __restrict__ bb,
    float* __restrict__ out, int M)
{
    const int wid  = threadIdx.x >> 6;
    const int lane = threadIdx.x & 63;
    const int row  = blockIdx.x * 4 + wid;
    if (row >= M) return;

    const size_t base = (size_t)row * 512 + lane * 8;
    float4 x0 = *(const float4*)(a + base);
    float4 x1 = *(const float4*)(a + base + 4);
    float v[8] = {x0.x, x0.y, x0.z, x0.w, x1.x, x1.y, x1.z, x1.w};
    for (int p = 1; p < nParts; p++) {
        const float* pp = a + (size_t)p * pstride + base;
        float4 r0 = *(const float4*)pp;
        float4 r1 = *(const float4*)(pp + 4);
        v[0] += r0.x; v[1] += r0.y; v[2] += r0.z; v[3] += r0.w;
        v[4] += r1.x; v[5] += r1.y; v[6] += r1.z; v[7] += r1.w;
    }
    if (res) {
        const float* rp = res + base;
        float4 r0 = *(const float4*)rp;
        float4 r1 = *(const float4*)(rp + 4);
        v[0] += r0.x; v[1] += r0.y; v[2] += r0.z; v[3] += r0.w;
        v[4] += r1.x; v[5] += r1.y; v[6] += r1.z; v[7] += r1.w;
    }
    float sum = 0.f, sq = 0.f;
#pragma unroll
    for (int j = 0; j < 8; j++) { sum += v[j]; sq = fmaf(v[j], v[j], sq); }
#pragma unroll
    for (int off = 1; off < 64; off <<= 1) {
        sum += __shfl_xor(sum, off);
        sq  += __shfl_xor(sq, off);
    }
    float mean = sum * (1.0f / 512.0f);
    float var  = sq * (1.0f / 512.0f) - mean * mean;
    float rstd = 1.0f / sqrtf(var + 1e-5f);

    const float* wp = w + lane * 8;
    const float* bp = bb + lane * 8;
    float ov[8];
#pragma unroll
    for (int j = 0; j < 8; j++) ov[j] = (v[j] - mean) * rstd * wp[j] + bp[j];
    float* op = out + base;
    *(float4*)op       = make_float4(ov[0], ov[1], ov[2], ov[3]);
    *(float4*)(op + 4) = make_float4(ov[4], ov[5], ov[6], ov[7]);
}

// ---------------------------------------------------------------------------
__global__ __launch_bounds__(256) void posembed_kernel(float* __restrict__ mem)
{
    int idx = blockIdx.x * 256 + threadIdx.x;
    if (idx >= NPAT_ * 256) return;
    int pos = idx >> 8;
    int i   = idx & 255;
    float div = expf((float)(2 * i) * (-9.21034037197618f / 512.0f));
    float ang = (float)pos * div;
    mem[(size_t)pos * 512 + 2 * i]     = sinf(ang);
    mem[(size_t)pos * 512 + 2 * i + 1] = cosf(ang);
}

__global__ __launch_bounds__(256) void winner_kernel(
    const int* __restrict__ mask, int* __restrict__ winner)
{
    int idx = blockIdx.x * 256 + threadIdx.x;
    if (idx >= B_ * NP_) return;
    int b = idx / NP_;
    atomicMax(&winner[b * NPAT_ + mask[idx]], idx % NP_);
}

__global__ __launch_bounds__(256) void scatter_kernel(
    const float* __restrict__ pred, const int* __restrict__ mask,
    const int* __restrict__ winner, float* __restrict__ out)
{
    int idx = blockIdx.x * 256 + threadIdx.x;
    if (idx >= B_ * NP_ * OUTD_) return;
    int e  = idx % OUTD_;
    int bp = idx / OUTD_;
    int p  = bp % NP_;
    int b  = bp / NP_;
    int mv = mask[b * NP_ + p];
    if (winner[b * NPAT_ + mv] != p) return;

    int f  = e / 768;
    int rm = e % 768;
    int c  = rm / 256;
    int r2 = rm % 256;
    int ph = r2 / 16;
    int pw = r2 % 16;
    int tt = mv / 196;
    int ss = mv % 196;
    int hi = ss / 14;
    int wi = ss % 14;

    size_t dst = ((size_t)((b * 16 + tt * 2 + f) * 3 + c)) * (224 * 224)
               + (size_t)(hi * 16 + ph) * 224 + (wi * 16 + pw);
    out[dst] = pred[(size_t)bp * OUTD_ + e];
}

// ---------------------------------------------------------------------------
extern "C" void kernel_launch(void* const* d_in, const int* in_sizes, int n_in,
                              void* d_out, int out_size, void* d_ws, size_t ws_size,
                              hipStream_t stream)
{
    const float* z       = (const float*)d_in[0];
    const int*   mask    = (const int*)d_in[1];
    const float* embed_w = (const float*)d_in[2];
    const float* embed_b = (const float*)d_in[3];
    const float* sa_qkv_w = (const float*)d_in[4];
    const float* sa_qkv_b = (const float*)d_in[5];
    const float* sa_out_w = (const float*)d_in[6];
    const float* sa_out_b = (const float*)d_in[7];
    const float* ca_qkv_w = (const float*)d_in[8];
    const float* ca_qkv_b = (const float*)d_in[9];
    const float* ca_out_w = (const float*)d_in[10];
    const float* ca_out_b = (const float*)d_in[11];
    const float* ff1_w = (const float*)d_in[12];
    const float* ff1_b = (const float*)d_in[13];
    const float* ff2_w = (const float*)d_in[14];
    const float* ff2_b = (const float*)d_in[15];
    const float* ln1_w = (const float*)d_in[16];
    const float* ln1_b = (const float*)d_in[17];
    const float* ln2_w = (const float*)d_in[18];
    const float* ln2_b = (const float*)d_in[19];
    const float* ln3_w = (const float*)d_in[20];
    const float* ln3_b = (const float*)d_in[21];
    const float* norm_w = (const float*)d_in[22];
    const float* norm_b = (const float*)d_in[23];
    const float* pred_w = (const float*)d_in[24];
    const float* pred_b = (const float*)d_in[25];

    float* ws  = (float*)d_ws;
    float* x   = ws;                          // [6272, 512]
    float* y   = x   + (size_t)M_ * 512;      // [6272, 2048]
    float* qkv = y   + (size_t)M_ * 2048;     // [6272, 1536]
    float* att = qkv + (size_t)M_ * 1536;     // [6272, 512]  (contiguous after qkv)
    float* mem = att + (size_t)M_ * 512;      // [1568, 512]
    float* ckv = mem + (size_t)NPAT_ * 512;   // [1568, 1024]
    int* winner = (int*)(ckv + (size_t)NPAT_ * 1024);   // [8, 1568]

    // conv buffers alias y (dead between qkv-GEMM and out-GEMM of each attn)
    short* kconvSA = (short*)y;
    short* vconvSA = kconvSA + (size_t)64 * NT_SA * 8192;
    short* kconvCA = vconvSA + (size_t)64 * NT_SA * 8192;
    short* vconvCA = kconvCA + (size_t)8 * NT_CA * 8192;

    // pre-split weight region (after winner); gated on ws_size
    short* wsb = (short*)(winner + B_ * NPAT_);
    const size_t o_embed = 0;                      // N=512 K=1024: 1024 st
    const size_t o_saqkv = o_embed + 1048576;      // 1536 st/layer
    const size_t o_saout = o_saqkv + 4ull * 1572864;
    const size_t o_caqkv = o_saout + 4ull * 524288;
    const size_t o_caout = o_caqkv + 4ull * 1572864;
    const size_t o_ff1   = o_caout + 4ull * 524288;
    const size_t o_ff2   = o_ff1 + 4ull * 2097152;
    const size_t o_pred  = o_ff2 + 4ull * 2097152;
    const size_t wsplit_shorts = o_pred + 1572864;
    const size_t need = (size_t)((char*)wsb - (char*)d_ws) + wsplit_shorts * 2;
    const bool pw = ws_size >= need;

    const size_t PS = (size_t)M_ * 512;   // partial-C stride (elems)

    if (pw) {
        conv_w_kernel<<<dim3(256, 1), 256, 0, stream>>>(embed_w, 0, 512, 1024, wsb + o_embed, 0);
        conv_w_kernel<<<dim3(384, 4), 256, 0, stream>>>(sa_qkv_w, 1536 * 512, 1536, 512, wsb + o_saqkv, 1572864);
        conv_w_kernel<<<dim3(128, 4), 256, 0, stream>>>(sa_out_w, 512 * 512, 512, 512, wsb + o_saout, 524288);
        conv_w_kernel<<<dim3(384, 4), 256, 0, stream>>>(ca_qkv_w, 1536 * 512, 1536, 512, wsb + o_caqkv, 1572864);
        conv_w_kernel<<<dim3(128, 4), 256, 0, stream>>>(ca_out_w, 512 * 512, 512, 512, wsb + o_caout, 524288);
        conv_w_kernel<<<dim3(512, 4), 256, 0, stream>>>(ff1_w, 2048 * 512, 2048, 512, wsb + o_ff1, 2097152);
        conv_w_kernel<<<dim3(512, 4), 256, 0, stream>>>(ff2_w, 512 * 2048, 512, 2048, wsb + o_ff2, 2097152);
        conv_w_kernel<<<dim3(384, 1), 256, 0, stream>>>(pred_w, 0, 1536, 512, wsb + o_pred, 0);
    }

    posembed_kernel<<<NPAT_, 256, 0, stream>>>(mem);

    // x = z @ embed_w.T + embed_b
    launch_gemm(pw, false, dim3(4, 49, 1), stream, z, ED_, embed_w, ED_,
                wsb + o_embed, 32, 0, embed_b, x, 512, 0, M_, 512, ED_, ED_);

    for (int l = 0; l < L_; l++) {
        const float* saw = sa_qkv_w + (size_t)l * 1536 * 512;
        const float* sab = sa_qkv_b + (size_t)l * 1536;
        const float* sow = sa_out_w + (size_t)l * 512 * 512;
        const float* sob = sa_out_b + (size_t)l * 512;
        const float* caw = ca_qkv_w + (size_t)l * 1536 * 512;
        const float* cab = ca_qkv_b + (size_t)l * 1536;
        const float* cow = ca_out_w + (size_t)l * 512 * 512;
        const float* cob = ca_out_b + (size_t)l * 512;
        const float* f1w = ff1_w + (size_t)l * 2048 * 512;
        const float* f1b = ff1_b + (size_t)l * 2048;
        const float* f2w = ff2_w + (size_t)l * 512 * 2048;
        const float* f2b = ff2_b + (size_t)l * 512;

        // ---- self-attention ----
        launch_gemm(pw, false, dim3(12, 49, 1), stream, x, 512, saw, 512,
                    wsb + o_saqkv + (size_t)l * 1572864, 96, 0, sab, qkv, 1536, 0, M_, 1536, 512, 512);
        conv_kv_kernel<0><<<dim3(NT_SA * 2, 64), 256, 0, stream>>>(
            qkv + 512, 1536, (size_t)NP_ * 1536, NP_, kconvSA, NT_SA);
        conv_kv_kernel<1><<<dim3(NT_SA * 2, 64), 256, 0, stream>>>(
            qkv + 1024, 1536, (size_t)NP_ * 1536, NP_, vconvSA, NT_SA);
        attn_mfma2_kernel<<<dim3(13, H_, B_), 256, 0, stream>>>(
            qkv, 1536, (size_t)NP_ * 1536, kconvSA, vconvSA, 8,
            att, NP_, NP_, NT_SA);
        // SA out-proj: split-K=2 -> partials in qkv region, reduce fused in LN
        launch_gemm(pw, false, dim3(4, 49, 2), stream, att, 512, sow, 512,
                    wsb + o_saout + (size_t)l * 524288, 32, 0, sob, qkv, 512, PS, M_, 512, 512, 256);
        ln_kernel<<<(M_ + 3) / 4, 256, 0, stream>>>(
            qkv, 2, PS, x, ln1_w + l * 512, ln1_b + l * 512, x, M_);

        // ---- cross-attention (K/V batch-shared) ----
        launch_gemm(pw, false, dim3(4, 49, 1), stream, x, 512, caw, 512,
                    wsb + o_caqkv + (size_t)l * 1572864, 96, 0, cab, qkv, 512, 0, M_, 512, 512, 512);
        launch_gemm(pw, false, dim3(8, 13, 1), stream, mem, 512, caw + 512 * 512, 512,
                    wsb + o_caqkv + (size_t)l * 1572864, 96, 32, cab + 512, ckv, 1024, 0, NPAT_, 1024, 512, 512);
        conv_kv_kernel<0><<<dim3(NT_CA * 2, 8), 256, 0, stream>>>(
            ckv, 1024, (size_t)0, NPAT_, kconvCA, NT_CA);
        conv_kv_kernel<1><<<dim3(NT_CA * 2, 8), 256, 0, stream>>>(
            ckv + 512, 1024, (size_t)0, NPAT_, vconvCA, NT_CA);
        attn_mfma2_kernel<<<dim3(13, H_, B_), 256, 0, stream>>>(
            qkv, 512, (size_t)NP_ * 512, kconvCA, vconvCA, 0,
            att, NP_, NPAT_, NT_CA);
        launch_gemm(pw, false, dim3(4, 49, 2), stream, att, 512, cow, 512,
                    wsb + o_caout + (size_t)l * 524288, 32, 0, cob, qkv, 512, PS, M_, 512, 512, 256);
        ln_kernel<<<(M_ + 3) / 4, 256, 0, stream>>>(
            qkv, 2, PS, x, ln2_w + l * 512, ln2_b + l * 512, x, M_);

        // ---- feed-forward ----
        launch_gemm(pw, true, dim3(16, 49, 1), stream, x, 512, f1w, 512,
                    wsb + o_ff1 + (size_t)l * 2097152, 128, 0, f1b, y, 2048, 0, M_, 2048, 512, 512);
        // FF2: split-K=4 -> partials span qkv (3 chunks) + att (1 chunk)
        launch_gemm(pw, false, dim3(4, 49, 4), stream, y, 2048, f2w, 2048,
                    wsb + o_ff2 + (size_t)l * 2097152, 32, 0, f2b, qkv, 512, PS, M_, 512, 2048, 512);
        ln_kernel<<<(M_ + 3) / 4, 256, 0, stream>>>(
            qkv, 4, PS, x, ln3_w + l * 512, ln3_b + l * 512, x, M_);
    }

    ln_kernel<<<(M_ + 3) / 4, 256, 0, stream>>>(x, 1, 0, nullptr, norm_w, norm_b, x, M_);
    launch_gemm(pw, false, dim3(12, 49, 1), stream, x, 512, pred_w, 512,
                wsb + o_pred, 96, 0, pred_b, qkv, 1536, 0, M_, 1536, 512, 512);

    hipMemsetAsync(d_out, 0, (size_t)out_size * sizeof(float), stream);
    hipMemsetAsync(winner, 0xFF, (size_t)B_ * NPAT_ * sizeof(int), stream);
    winner_kernel<<<(B_ * NP_ + 255) / 256, 256, 0, stream>>>(mask, winner);
    scatter_kernel<<<(B_ * NP_ * OUTD_ + 255) / 256, 256, 0, stream>>>(
        qkv, mask, winner, (float*)d_out);
}

// Round 8
// 1977.563 us; speedup vs baseline: 2.7678x; 1.0765x over previous
//
#include <hip/hip_runtime.h>
#include <hip/hip_bf16.h>
#include <math.h>

// Problem constants
#define B_    8
#define NP_   784
#define ED_   1024
#define D_    512
#define H_    8
#define DH_   64
#define NPAT_ 1568
#define FF_   2048
#define L_    4
#define OUTD_ 1536
#define M_    (B_ * NP_)   // 6272

#define NT_SA 13           // ceil(784/64)
#define NT_CA 25           // ceil(1568/64)

typedef __attribute__((ext_vector_type(8))) short bf16x8;
typedef __attribute__((ext_vector_type(4))) float f32x4;

// split x = hi + lo, both bf16 (truncation: x - hi exact, dropped term ~2^-16 rel)
static __device__ inline void split_bf16(float x, unsigned short& h, unsigned short& l)
{
    unsigned bits = __float_as_uint(x);
    h = (unsigned short)(bits >> 16);
    float r = x - __uint_as_float(bits & 0xFFFF0000u);
    l = (unsigned short)(__float_as_uint(r) >> 16);
}

// ---------------------------------------------------------------------------
// Weight pre-split: W[N,K] fp32 -> hi/lo bf16 planes in B-frag-linear order.
// (unchanged, validated round 7)
// ---------------------------------------------------------------------------
__global__ __launch_bounds__(256) void conv_w_kernel(
    const float* __restrict__ src, size_t lss, int N, int K,
    short* __restrict__ dst, size_t lsd)
{
    const int t  = threadIdx.x;
    const int l  = blockIdx.y;
    const int gs = blockIdx.x * 4 + (t >> 6);
    const int m  = t & 63;
    const int NB16 = N >> 4;
    const int kb = gs / NB16;
    const int ns = gs % NB16;

    const float* p = src + (size_t)l * lss + (size_t)(ns * 16 + (m & 15)) * K
                   + kb * 32 + (m >> 4) * 8;
    float4 a0 = *(const float4*)p;
    float4 a1 = *(const float4*)(p + 4);
    float xv[8] = {a0.x, a0.y, a0.z, a0.w, a1.x, a1.y, a1.z, a1.w};
    union { short s_[8]; bf16x8 v; } hi, lo;
#pragma unroll
    for (int e = 0; e < 8; e++) {
        unsigned short hh, ll;
        split_bf16(xv[e], hh, ll);
        hi.s_[e] = (short)hh; lo.s_[e] = (short)ll;
    }
    short* o = dst + (size_t)l * lsd + (size_t)gs * 1024 + m * 8;
    *(bf16x8*)o         = hi.v;
    *(bf16x8*)(o + 512) = lo.v;
}

// ---------------------------------------------------------------------------
// Split-bf16 MFMA GEMM (unchanged, validated round 7): split-K + pre-split W.
// ---------------------------------------------------------------------------
template <int ACT, int PW>
__global__ __launch_bounds__(256, 2) void gemm_mfma_kernel(
    const float* __restrict__ A, int lda,
    const float* __restrict__ W, int ldw,
    const short* __restrict__ wsp, int NB16, int cOff,
    const float* __restrict__ bias,
    float* __restrict__ C, int ldc, size_t cstride,
    int M, int N, int K, int KC)
{
    __shared__ short sAh[8 * 512];
    __shared__ short sAl[8 * 512];
    __shared__ short sBh[8 * 512];
    __shared__ short sBl[8 * 512];

    const int t    = threadIdx.x;
    const int lane = t & 63;
    const int wid  = t >> 6;
    const int wr   = wid >> 1;
    const int wc   = wid & 1;
    const int bm   = blockIdx.y * 128;
    const int bn   = blockIdx.x * 128;
    const int kBeg = blockIdx.z * KC;
    C += (size_t)blockIdx.z * cstride;

    const int srow  = t >> 1;
    const int shalf = t & 1;

    int arow = bm + srow; if (arow >= M) arow = M - 1;
    const float* aptr = A + (size_t)arow * lda + shalf * 16;
    const float* wptr = (PW == 0) ? (W + (size_t)(bn + srow) * ldw + shalf * 16) : nullptr;

    const int wbase = (srow >> 4) * 512 + (srow & 15) * 8 + shalf * 256;

    f32x4 acc[4][4];
    {
        const int col = bn + wc * 64 + (lane & 15);
#pragma unroll
        for (int j = 0; j < 4; j++) {
            float bv = (blockIdx.z == 0) ? bias[col + j * 16] : 0.0f;
            for (int i = 0; i < 4; i++) acc[i][j] = (f32x4)(bv);
        }
    }

    for (int k0 = kBeg; k0 < kBeg + KC; k0 += 32) {
        float4 av[4];
#pragma unroll
        for (int q = 0; q < 4; q++) av[q] = *(const float4*)(aptr + k0 + q * 4);

        float4 wv[4];
        bf16x8 bh0, bh1, bl0, bl1;
        if constexpr (PW == 0) {
#pragma unroll
            for (int q = 0; q < 4; q++) wv[q] = *(const float4*)(wptr + k0 + q * 4);
        } else {
            const short* gb = wsp + ((size_t)(k0 >> 5) * NB16 + (bn >> 4) + cOff) * 1024
                            + (t >> 5) * 1024 + (t & 31) * 16;
            bh0 = *(const bf16x8*)gb;
            bh1 = *(const bf16x8*)(gb + 8);
            bl0 = *(const bf16x8*)(gb + 512);
            bl1 = *(const bf16x8*)(gb + 520);
        }
        __syncthreads();

        {
            union { short s[16]; bf16x8 v[2]; } ah, al;
#pragma unroll
            for (int q = 0; q < 4; q++) {
                const float* ap = (const float*)&av[q];
#pragma unroll
                for (int e = 0; e < 4; e++) {
                    unsigned short hh, ll;
                    split_bf16(ap[e], hh, ll);
                    ah.s[q * 4 + e] = (short)hh; al.s[q * 4 + e] = (short)ll;
                }
            }
            *(bf16x8*)&sAh[wbase]       = ah.v[0];
            *(bf16x8*)&sAh[wbase + 128] = ah.v[1];
            *(bf16x8*)&sAl[wbase]       = al.v[0];
            *(bf16x8*)&sAl[wbase + 128] = al.v[1];
        }
        if constexpr (PW == 0) {
            union { short s[16]; bf16x8 v[2]; } wh, wl;
#pragma unroll
            for (int q = 0; q < 4; q++) {
                const float* wp = (const float*)&wv[q];
#pragma unroll
                for (int e = 0; e < 4; e++) {
                    unsigned short hh, ll;
                    split_bf16(wp[e], hh, ll);
                    wh.s[q * 4 + e] = (short)hh; wl.s[q * 4 + e] = (short)ll;
                }
            }
            *(bf16x8*)&sBh[wbase]       = wh.v[0];
            *(bf16x8*)&sBh[wbase + 128] = wh.v[1];
            *(bf16x8*)&sBl[wbase]       = wl.v[0];
            *(bf16x8*)&sBl[wbase + 128] = wl.v[1];
        } else {
            *(bf16x8*)&sBh[t * 16]     = bh0;
            *(bf16x8*)&sBh[t * 16 + 8] = bh1;
            *(bf16x8*)&sBl[t * 16]     = bl0;
            *(bf16x8*)&sBl[t * 16 + 8] = bl1;
        }
        __syncthreads();

        bf16x8 ahf[4], alf[4], bhf[4], blf[4];
#pragma unroll
        for (int i = 0; i < 4; i++) {
            int sa = (wr * 4 + i) * 512 + lane * 8;
            ahf[i] = *(const bf16x8*)&sAh[sa];
            alf[i] = *(const bf16x8*)&sAl[sa];
        }
#pragma unroll
        for (int j = 0; j < 4; j++) {
            int sb = (wc * 4 + j) * 512 + lane * 8;
            bhf[j] = *(const bf16x8*)&sBh[sb];
            blf[j] = *(const bf16x8*)&sBl[sb];
        }
#pragma unroll
        for (int i = 0; i < 4; i++)
#pragma unroll
            for (int j = 0; j < 4; j++) {
                acc[i][j] = __builtin_amdgcn_mfma_f32_16x16x32_bf16(ahf[i], bhf[j], acc[i][j], 0, 0, 0);
                acc[i][j] = __builtin_amdgcn_mfma_f32_16x16x32_bf16(ahf[i], blf[j], acc[i][j], 0, 0, 0);
                acc[i][j] = __builtin_amdgcn_mfma_f32_16x16x32_bf16(alf[i], bhf[j], acc[i][j], 0, 0, 0);
            }
    }

#pragma unroll
    for (int i = 0; i < 4; i++) {
        int row0 = bm + wr * 64 + i * 16 + ((lane >> 4) << 2);
#pragma unroll
        for (int r = 0; r < 4; r++) {
            int row = row0 + r;
            if (row < M) {
#pragma unroll
                for (int j = 0; j < 4; j++) {
                    int col = bn + wc * 64 + j * 16 + (lane & 15);
                    float v = acc[i][j][r];
                    if (ACT == 1) v = 0.5f * v * (1.0f + erff(v * 0.70710678118654752f));
                    C[(size_t)row * ldc + col] = v;
                }
            }
        }
    }
}

static inline void launch_gemm(bool pw, bool act, dim3 grid, hipStream_t st,
    const float* A, int lda, const float* W, int ldw,
    const short* wsp, int NB16, int cOff, const float* bias,
    float* C, int ldc, size_t cstride, int M, int N, int K, int KC)
{
    if (pw) {
        if (act) gemm_mfma_kernel<1,1><<<grid,256,0,st>>>(A,lda,W,ldw,wsp,NB16,cOff,bias,C,ldc,cstride,M,N,K,KC);
        else     gemm_mfma_kernel<0,1><<<grid,256,0,st>>>(A,lda,W,ldw,wsp,NB16,cOff,bias,C,ldc,cstride,M,N,K,KC);
    } else {
        if (act) gemm_mfma_kernel<1,0><<<grid,256,0,st>>>(A,lda,W,ldw,wsp,NB16,cOff,bias,C,ldc,cstride,M,N,K,KC);
        else     gemm_mfma_kernel<0,0><<<grid,256,0,st>>>(A,lda,W,ldw,wsp,NB16,cOff,bias,C,ldc,cstride,M,N,K,KC);
    }
}

// ---------------------------------------------------------------------------
// K/V pre-conversion for attention (unchanged, validated round 6).
// ---------------------------------------------------------------------------
template <int MODE>
__global__ __launch_bounds__(256) void conv_kv_kernel(
    const float* __restrict__ src, int ld, size_t bstride, int rows,
    short* __restrict__ out, int NT)
{
    const int t    = threadIdx.x;
    const int half = blockIdx.x & 1;
    const int tile = blockIdx.x >> 1;
    const int bh   = blockIdx.y;
    const int b    = bh >> 3;
    const int h    = bh & 7;
    const int s    = half * 4 + (t >> 6);
    const int m    = t & 63;

    float xv[8];
    if (MODE == 0) {
        int kv = tile * 64 + (s & 3) * 16 + (m & 15);
        if (kv >= rows) kv = rows - 1;
        int dh = (s >> 2) * 32 + (m >> 4) * 8;
        const float* p = src + (size_t)b * bstride + (size_t)kv * ld + h * 64 + dh;
        float4 a0 = *(const float4*)p;
        float4 a1 = *(const float4*)(p + 4);
        xv[0] = a0.x; xv[1] = a0.y; xv[2] = a0.z; xv[3] = a0.w;
        xv[4] = a1.x; xv[5] = a1.y; xv[6] = a1.z; xv[7] = a1.w;
    } else {
        int dh  = (s & 3) * 16 + (m & 15);
        int kv0 = tile * 64 + (s >> 2) * 32 + (m >> 4) * 8;
        const float* p = src + (size_t)b * bstride + h * 64 + dh;
#pragma unroll
        for (int j = 0; j < 8; j++) {
            int kv = kv0 + j; if (kv >= rows) kv = rows - 1;
            xv[j] = p[(size_t)kv * ld];
        }
    }
    union { short s_[8]; bf16x8 v; } hi, lo;
#pragma unroll
    for (int e = 0; e < 8; e++) {
        unsigned short hh, ll;
        split_bf16(xv[e], hh, ll);
        hi.s_[e] = (short)hh; lo.s_[e] = (short)ll;
    }
    short* o = out + ((size_t)bh * NT + tile) * 8192 + s * 512 + m * 8;
    *(bf16x8*)o          = hi.v;
    *(bf16x8*)(o + 4096) = lo.v;
}

// ---------------------------------------------------------------------------
// MFMA flash attention v3:
//  - P hi-plane only in PV (ph*vh + ph*vl); lsum accumulated from truncated
//    ph so weights = ph/sum(ph) stay consistent. LDS 48->40KB, 4 blocks/CU.
//  - 1D grid with XCD-aware decode: SA groups one batch per XCD (KV 3.3MB
//    L2-resident), CA groups one head per XCD (KV 800KB).
//  - s_setprio(1) around MFMA clusters.
// ---------------------------------------------------------------------------
__global__ __launch_bounds__(256, 4) void attn_mfma3_kernel(
    const float* __restrict__ Q, int ldq, size_t qStride,
    const short* __restrict__ kconv, const short* __restrict__ vconv,
    int saMode,
    float* __restrict__ O,
    int qLen, int kvLen, int NT)
{
    __shared__ short sK[8192];
    __shared__ short sV[8192];
    __shared__ short sP[4][1024];   // P hi plane only (per wave 2 KB)

    const int t    = threadIdx.x;
    const int lane = t & 63;
    const int wid  = t >> 6;
    const int g    = lane >> 4;
    const int l15  = lane & 15;

    // XCD-aware decode of flat 832-block grid (bijective: 832 = 8*8*13)
    const int id  = blockIdx.x;
    const int xcd = id & 7;
    const int sbl = id >> 3;          // 0..103
    const int qt  = sbl % 13;
    const int jj  = sbl / 13;         // 0..7
    const int b   = saMode ? xcd : jj;
    const int h   = saMode ? jj : xcd;
    const int bh  = saMode ? (b * 8 + h) : h;
    const int hoff = h * 64;

    int qrow = qt * 64 + wid * 16 + l15;
    int qcl  = qrow < qLen ? qrow : qLen - 1;
    const float* qp = Q + (size_t)b * qStride + (size_t)qcl * ldq + hoff + g * 8;
    bf16x8 qh[2], ql[2];
#pragma unroll
    for (int ks = 0; ks < 2; ks++) {
        float4 x0 = *(const float4*)(qp + ks * 32);
        float4 x1 = *(const float4*)(qp + ks * 32 + 4);
        float xv[8] = {x0.x, x0.y, x0.z, x0.w, x1.x, x1.y, x1.z, x1.w};
        union { short s[8]; bf16x8 v; } hi, lo;
#pragma unroll
        for (int e = 0; e < 8; e++) {
            unsigned short hh, ll;
            split_bf16(xv[e] * 0.125f, hh, ll);
            hi.s[e] = (short)hh; lo.s[e] = (short)ll;
        }
        qh[ks] = hi.v; ql[ks] = lo.v;
    }

    f32x4 o[4];
#pragma unroll
    for (int f = 0; f < 4; f++) o[f] = (f32x4)(0.0f);
    float m = -1e30f, lsum = 0.0f;

    char* const phw = (char*)&sP[wid][0];

    for (int tile = 0; tile < NT; ++tile) {
        const short* kt = kconv + ((size_t)bh * NT + tile) * 8192;
        const short* vt = vconv + ((size_t)bh * NT + tile) * 8192;
        bf16x8 kreg[4], vreg[4];
#pragma unroll
        for (int i = 0; i < 4; i++) {
            kreg[i] = *(const bf16x8*)(kt + i * 2048 + t * 8);
            vreg[i] = *(const bf16x8*)(vt + i * 2048 + t * 8);
        }
        __syncthreads();
#pragma unroll
        for (int i = 0; i < 4; i++) {
            *(bf16x8*)&sK[i * 2048 + t * 8] = kreg[i];
            *(bf16x8*)&sV[i * 2048 + t * 8] = vreg[i];
        }
        __syncthreads();

        // ---- QK^T (swapped): S^T[kv][q] ----
        f32x4 s[4];
#pragma unroll
        for (int f = 0; f < 4; f++) s[f] = (f32x4)(0.0f);
        __builtin_amdgcn_s_setprio(1);
#pragma unroll
        for (int f = 0; f < 4; f++)
#pragma unroll
            for (int ks = 0; ks < 2; ks++) {
                int off = (ks * 4 + f) * 512 + lane * 8;
                bf16x8 kh8 = *(const bf16x8*)&sK[off];
                bf16x8 kl8 = *(const bf16x8*)&sK[off + 4096];
                s[f] = __builtin_amdgcn_mfma_f32_16x16x32_bf16(kh8, qh[ks], s[f], 0, 0, 0);
                s[f] = __builtin_amdgcn_mfma_f32_16x16x32_bf16(kh8, ql[ks], s[f], 0, 0, 0);
                s[f] = __builtin_amdgcn_mfma_f32_16x16x32_bf16(kl8, qh[ks], s[f], 0, 0, 0);
            }
        __builtin_amdgcn_s_setprio(0);

        // ---- softmax (per q = l15) ----
        int kv0 = tile * 64;
        float tmax = -1e30f;
#pragma unroll
        for (int f = 0; f < 4; f++)
#pragma unroll
            for (int r = 0; r < 4; r++) {
                float sv = s[f][r];
                int kvg = kv0 + 16 * f + g * 4 + r;
                sv = (kvg < kvLen) ? sv : -1e30f;
                s[f][r] = sv;
                tmax = fmaxf(tmax, sv);
            }
        tmax = fmaxf(tmax, __shfl_xor(tmax, 16));
        tmax = fmaxf(tmax, __shfl_xor(tmax, 32));
        float mnew  = fmaxf(m, tmax);
        float alpha = __expf(m - mnew);
        m = mnew;
        lsum *= alpha;

        // P = exp(S - m) -> truncate to bf16 hi; lsum from truncated values
#pragma unroll
        for (int f = 0; f < 4; f++) {
            unsigned hb[4];
#pragma unroll
            for (int r = 0; r < 4; r++) {
                float p = __expf(s[f][r] - mnew);
                hb[r] = __float_as_uint(p) >> 16;
                lsum += __uint_as_float(hb[r] << 16);
            }
            uint2 uh;
            uh.x = hb[0] | (hb[1] << 16);
            uh.y = hb[2] | (hb[3] << 16);
            int wa = (l15 * 128 + f * 32 + g * 8) ^ ((l15 & 7) << 4);
            *(uint2*)(phw + wa) = uh;
        }

        // rescale O by alpha of its q rows (q = g*4+r lives at lane g*4+r)
        {
            float a0 = __shfl(alpha, g * 4 + 0);
            float a1 = __shfl(alpha, g * 4 + 1);
            float a2 = __shfl(alpha, g * 4 + 2);
            float a3 = __shfl(alpha, g * 4 + 3);
#pragma unroll
            for (int f = 0; f < 4; f++) {
                o[f][0] *= a0; o[f][1] *= a1; o[f][2] *= a2; o[f][3] *= a3;
            }
        }

        // ---- PV: O += P_hi * (V_hi + V_lo) ----
        __builtin_amdgcn_s_setprio(1);
#pragma unroll
        for (int ks = 0; ks < 2; ks++) {
            int pa = (l15 * 128 + ks * 64 + g * 16) ^ ((l15 & 7) << 4);
            bf16x8 p_h = *(const bf16x8*)(phw + pa);
#pragma unroll
            for (int f = 0; f < 4; f++) {
                int off = (ks * 4 + f) * 512 + lane * 8;
                bf16x8 vh8 = *(const bf16x8*)&sV[off];
                bf16x8 vl8 = *(const bf16x8*)&sV[off + 4096];
                o[f] = __builtin_amdgcn_mfma_f32_16x16x32_bf16(p_h, vh8, o[f], 0, 0, 0);
                o[f] = __builtin_amdgcn_mfma_f32_16x16x32_bf16(p_h, vl8, o[f], 0, 0, 0);
            }
        }
        __builtin_amdgcn_s_setprio(0);
    }

    lsum += __shfl_xor(lsum, 16);
    lsum += __shfl_xor(lsum, 32);
    float linv = 1.0f / lsum;
    float lr0 = __shfl(linv, g * 4 + 0);
    float lr1 = __shfl(linv, g * 4 + 1);
    float lr2 = __shfl(linv, g * 4 + 2);
    float lr3 = __shfl(linv, g * 4 + 3);
    float lr[4] = {lr0, lr1, lr2, lr3};

    int row0 = qt * 64 + wid * 16 + g * 4;
#pragma unroll
    for (int r = 0; r < 4; r++) {
        int row = row0 + r;
        if (row < qLen) {
            float* op = O + ((size_t)b * qLen + row) * 512 + hoff + l15;
#pragma unroll
            for (int f = 0; f < 4; f++)
                op[f * 16] = o[f][r] * lr[r];
        }
    }
}

// ---------------------------------------------------------------------------
// LayerNorm over D=512 with fused split-K reduction (unchanged, round 7).
// ---------------------------------------------------------------------------
__global__ __launch_bounds__(256) void ln_kernel(
    const float* __restrict__ a, int nParts, size_t pstride,
    const float* __restrict__ res,
    const float* __restrict__ w, const float* __restrict__ bb,
    float* __restrict__ out, int M)
{
    const int wid  = threadIdx.x >> 6;
    const int lane = threadIdx.x & 63;
    const int row  = blockIdx.x * 4 + wid;
    if (row >= M) return;

    const size_t base = (size_t)row * 512 + lane * 8;
    float4 x0 = *(const float4*)(a + base);
    float4 x1 = *(const float4*)(a + base + 4);
    float v[8] = {x0.x, x0.y, x0.z, x0.w, x1.x, x1.y, x1.z, x1.w};
    for (int p = 1; p < nParts; p++) {
        const float* pp = a + (size_t)p * pstride + base;
        float4 r0 = *(const float4*)pp;
        float4 r1 = *(const float4*)(pp + 4);
        v[0] += r0.x; v[1] += r0.y; v[2] += r0.z; v[3] += r0.w;
        v[4] += r1.x; v[5] += r1.y; v[6] += r1.z; v[7] += r1.w;
    }
    if (res) {
        const float* rp = res + base;
        float4 r0 = *(const float4*)rp;
        float4 r1 = *(const float4*)(rp + 4);
        v[0] += r0.x; v[1] += r0.y; v[2] += r0.z; v[3] += r0.w;
        v[4] += r1.x; v[5] += r1.y; v[6] += r1.z; v[7] += r1.w;
    }
    float sum = 0.f, sq = 0.f;
#pragma unroll
    for (int j = 0; j < 8; j++) { sum += v[j]; sq = fmaf(v[j], v[j], sq); }
#pragma unroll
    for (int off = 1; off < 64; off <<= 1) {
        sum += __shfl_xor(sum, off);
        sq  += __shfl_xor(sq, off);
    }
    float mean = sum * (1.0f / 512.0f);
    float var  = sq * (1.0f / 512.0f) - mean * mean;
    float rstd = 1.0f / sqrtf(var + 1e-5f);

    const float* wp = w + lane * 8;
    const float* bp = bb + lane * 8;
    float ov[8];
#pragma unroll
    for (int j = 0; j < 8; j++) ov[j] = (v[j] - mean) * rstd * wp[j] + bp[j];
    float* op = out + base;
    *(float4*)op       = make_float4(ov[0], ov[1], ov[2], ov[3]);
    *(float4*)(op + 4) = make_float4(ov[4], ov[5], ov[6], ov[7]);
}

// ---------------------------------------------------------------------------
__global__ __launch_bounds__(256) void posembed_kernel(float* __restrict__ mem)
{
    int idx = blockIdx.x * 256 + threadIdx.x;
    if (idx >= NPAT_ * 256) return;
    int pos = idx >> 8;
    int i   = idx & 255;
    float div = expf((float)(2 * i) * (-9.21034037197618f / 512.0f));
    float ang = (float)pos * div;
    mem[(size_t)pos * 512 + 2 * i]     = sinf(ang);
    mem[(size_t)pos * 512 + 2 * i + 1] = cosf(ang);
}

__global__ __launch_bounds__(256) void winner_kernel(
    const int* __restrict__ mask, int* __restrict__ winner)
{
    int idx = blockIdx.x * 256 + threadIdx.x;
    if (idx >= B_ * NP_) return;
    int b = idx / NP_;
    atomicMax(&winner[b * NPAT_ + mask[idx]], idx % NP_);
}

__global__ __launch_bounds__(256) void scatter_kernel(
    const float* __restrict__ pred, const int* __restrict__ mask,
    const int* __restrict__ winner, float* __restrict__ out)
{
    int idx = blockIdx.x * 256 + threadIdx.x;
    if (idx >= B_ * NP_ * OUTD_) return;
    int e  = idx % OUTD_;
    int bp = idx / OUTD_;
    int p  = bp % NP_;
    int b  = bp / NP_;
    int mv = mask[b * NP_ + p];
    if (winner[b * NPAT_ + mv] != p) return;

    int f  = e / 768;
    int rm = e % 768;
    int c  = rm / 256;
    int r2 = rm % 256;
    int ph = r2 / 16;
    int pw = r2 % 16;
    int tt = mv / 196;
    int ss = mv % 196;
    int hi = ss / 14;
    int wi = ss % 14;

    size_t dst = ((size_t)((b * 16 + tt * 2 + f) * 3 + c)) * (224 * 224)
               + (size_t)(hi * 16 + ph) * 224 + (wi * 16 + pw);
    out[dst] = pred[(size_t)bp * OUTD_ + e];
}

// ---------------------------------------------------------------------------
extern "C" void kernel_launch(void* const* d_in, const int* in_sizes, int n_in,
                              void* d_out, int out_size, void* d_ws, size_t ws_size,
                              hipStream_t stream)
{
    const float* z       = (const float*)d_in[0];
    const int*   mask    = (const int*)d_in[1];
    const float* embed_w = (const float*)d_in[2];
    const float* embed_b = (const float*)d_in[3];
    const float* sa_qkv_w = (const float*)d_in[4];
    const float* sa_qkv_b = (const float*)d_in[5];
    const float* sa_out_w = (const float*)d_in[6];
    const float* sa_out_b = (const float*)d_in[7];
    const float* ca_qkv_w = (const float*)d_in[8];
    const float* ca_qkv_b = (const float*)d_in[9];
    const float* ca_out_w = (const float*)d_in[10];
    const float* ca_out_b = (const float*)d_in[11];
    const float* ff1_w = (const float*)d_in[12];
    const float* ff1_b = (const float*)d_in[13];
    const float* ff2_w = (const float*)d_in[14];
    const float* ff2_b = (const float*)d_in[15];
    const float* ln1_w = (const float*)d_in[16];
    const float* ln1_b = (const float*)d_in[17];
    const float* ln2_w = (const float*)d_in[18];
    const float* ln2_b = (const float*)d_in[19];
    const float* ln3_w = (const float*)d_in[20];
    const float* ln3_b = (const float*)d_in[21];
    const float* norm_w = (const float*)d_in[22];
    const float* norm_b = (const float*)d_in[23];
    const float* pred_w = (const float*)d_in[24];
    const float* pred_b = (const float*)d_in[25];

    float* ws  = (float*)d_ws;
    float* x   = ws;                          // [6272, 512]
    float* y   = x   + (size_t)M_ * 512;      // [6272, 2048]
    float* qkv = y   + (size_t)M_ * 2048;     // [6272, 1536]
    float* att = qkv + (size_t)M_ * 1536;     // [6272, 512]
    float* mem = att + (size_t)M_ * 512;      // [1568, 512]
    float* ckv = mem + (size_t)NPAT_ * 512;   // [1568, 1024]
    int* winner = (int*)(ckv + (size_t)NPAT_ * 1024);   // [8, 1568]

    short* kconvSA = (short*)y;
    short* vconvSA = kconvSA + (size_t)64 * NT_SA * 8192;
    short* kconvCA = vconvSA + (size_t)64 * NT_SA * 8192;
    short* vconvCA = kconvCA + (size_t)8 * NT_CA * 8192;

    short* wsb = (short*)(winner + B_ * NPAT_);
    const size_t o_embed = 0;
    const size_t o_saqkv = o_embed + 1048576;
    const size_t o_saout = o_saqkv + 4ull * 1572864;
    const size_t o_caqkv = o_saout + 4ull * 524288;
    const size_t o_caout = o_caqkv + 4ull * 1572864;
    const size_t o_ff1   = o_caout + 4ull * 524288;
    const size_t o_ff2   = o_ff1 + 4ull * 2097152;
    const size_t o_pred  = o_ff2 + 4ull * 2097152;
    const size_t wsplit_shorts = o_pred + 1572864;
    const size_t need = (size_t)((char*)wsb - (char*)d_ws) + wsplit_shorts * 2;
    const bool pw = ws_size >= need;

    const size_t PS = (size_t)M_ * 512;

    if (pw) {
        conv_w_kernel<<<dim3(256, 1), 256, 0, stream>>>(embed_w, 0, 512, 1024, wsb + o_embed, 0);
        conv_w_kernel<<<dim3(384, 4), 256, 0, stream>>>(sa_qkv_w, 1536 * 512, 1536, 512, wsb + o_saqkv, 1572864);
        conv_w_kernel<<<dim3(128, 4), 256, 0, stream>>>(sa_out_w, 512 * 512, 512, 512, wsb + o_saout, 524288);
        conv_w_kernel<<<dim3(384, 4), 256, 0, stream>>>(ca_qkv_w, 1536 * 512, 1536, 512, wsb + o_caqkv, 1572864);
        conv_w_kernel<<<dim3(128, 4), 256, 0, stream>>>(ca_out_w, 512 * 512, 512, 512, wsb + o_caout, 524288);
        conv_w_kernel<<<dim3(512, 4), 256, 0, stream>>>(ff1_w, 2048 * 512, 2048, 512, wsb + o_ff1, 2097152);
        conv_w_kernel<<<dim3(512, 4), 256, 0, stream>>>(ff2_w, 512 * 2048, 512, 2048, wsb + o_ff2, 2097152);
        conv_w_kernel<<<dim3(384, 1), 256, 0, stream>>>(pred_w, 0, 1536, 512, wsb + o_pred, 0);
    }

    posembed_kernel<<<NPAT_, 256, 0, stream>>>(mem);

    launch_gemm(pw, false, dim3(4, 49, 1), stream, z, ED_, embed_w, ED_,
                wsb + o_embed, 32, 0, embed_b, x, 512, 0, M_, 512, ED_, ED_);

    for (int l = 0; l < L_; l++) {
        const float* saw = sa_qkv_w + (size_t)l * 1536 * 512;
        const float* sab = sa_qkv_b + (size_t)l * 1536;
        const float* sow = sa_out_w + (size_t)l * 512 * 512;
        const float* sob = sa_out_b + (size_t)l * 512;
        const float* caw = ca_qkv_w + (size_t)l * 1536 * 512;
        const float* cab = ca_qkv_b + (size_t)l * 1536;
        const float* cow = ca_out_w + (size_t)l * 512 * 512;
        const float* cob = ca_out_b + (size_t)l * 512;
        const float* f1w = ff1_w + (size_t)l * 2048 * 512;
        const float* f1b = ff1_b + (size_t)l * 2048;
        const float* f2w = ff2_w + (size_t)l * 512 * 2048;
        const float* f2b = ff2_b + (size_t)l * 512;

        // ---- self-attention ----
        launch_gemm(pw, false, dim3(12, 49, 1), stream, x, 512, saw, 512,
                    wsb + o_saqkv + (size_t)l * 1572864, 96, 0, sab, qkv, 1536, 0, M_, 1536, 512, 512);
        conv_kv_kernel<0><<<dim3(NT_SA * 2, 64), 256, 0, stream>>>(
            qkv + 512, 1536, (size_t)NP_ * 1536, NP_, kconvSA, NT_SA);
        conv_kv_kernel<1><<<dim3(NT_SA * 2, 64), 256, 0, stream>>>(
            qkv + 1024, 1536, (size_t)NP_ * 1536, NP_, vconvSA, NT_SA);
        attn_mfma3_kernel<<<832, 256, 0, stream>>>(
            qkv, 1536, (size_t)NP_ * 1536, kconvSA, vconvSA, 1,
            att, NP_, NP_, NT_SA);
        launch_gemm(pw, false, dim3(4, 49, 2), stream, att, 512, sow, 512,
                    wsb + o_saout + (size_t)l * 524288, 32, 0, sob, qkv, 512, PS, M_, 512, 512, 256);
        ln_kernel<<<(M_ + 3) / 4, 256, 0, stream>>>(
            qkv, 2, PS, x, ln1_w + l * 512, ln1_b + l * 512, x, M_);

        // ---- cross-attention (K/V batch-shared) ----
        launch_gemm(pw, false, dim3(4, 49, 1), stream, x, 512, caw, 512,
                    wsb + o_caqkv + (size_t)l * 1572864, 96, 0, cab, qkv, 512, 0, M_, 512, 512, 512);
        launch_gemm(pw, false, dim3(8, 13, 1), stream, mem, 512, caw + 512 * 512, 512,
                    wsb + o_caqkv + (size_t)l * 1572864, 96, 32, cab + 512, ckv, 1024, 0, NPAT_, 1024, 512, 512);
        conv_kv_kernel<0><<<dim3(NT_CA * 2, 8), 256, 0, stream>>>(
            ckv, 1024, (size_t)0, NPAT_, kconvCA, NT_CA);
        conv_kv_kernel<1><<<dim3(NT_CA * 2, 8), 256, 0, stream>>>(
            ckv + 512, 1024, (size_t)0, NPAT_, vconvCA, NT_CA);
        attn_mfma3_kernel<<<832, 256, 0, stream>>>(
            qkv, 512, (size_t)NP_ * 512, kconvCA, vconvCA, 0,
            att, NP_, NPAT_, NT_CA);
        launch_gemm(pw, false, dim3(4, 49, 2), stream, att, 512, cow, 512,
                    wsb + o_caout + (size_t)l * 524288, 32, 0, cob, qkv, 512, PS, M_, 512, 512, 256);
        ln_kernel<<<(M_ + 3) / 4, 256, 0, stream>>>(
            qkv, 2, PS, x, ln2_w + l * 512, ln2_b + l * 512, x, M_);

        // ---- feed-forward ----
        launch_gemm(pw, true, dim3(16, 49, 1), stream, x, 512, f1w, 512,
                    wsb + o_ff1 + (size_t)l * 2097152, 128, 0, f1b, y, 2048, 0, M_, 2048, 512, 512);
        launch_gemm(pw, false, dim3(4, 49, 4), stream, y, 2048, f2w, 2048,
                    wsb + o_ff2 + (size_t)l * 2097152, 32, 0, f2b, qkv, 512, PS, M_, 512, 2048, 512);
        ln_kernel<<<(M_ + 3) / 4, 256, 0, stream>>>(
            qkv, 4, PS, x, ln3_w + l * 512, ln3_b + l * 512, x, M_);
    }

    ln_kernel<<<(M_ + 3) / 4, 256, 0, stream>>>(x, 1, 0, nullptr, norm_w, norm_b, x, M_);
    launch_gemm(pw, false, dim3(12, 49, 1), stream, x, 512, pred_w, 512,
                wsb + o_pred, 96, 0, pred_b, qkv, 1536, 0, M_, 1536, 512, 512);

    hipMemsetAsync(d_out, 0, (size_t)out_size * sizeof(float), stream);
    hipMemsetAsync(winner, 0xFF, (size_t)B_ * NPAT_ * sizeof(int), stream);
    winner_kernel<<<(B_ * NP_ + 255) / 256, 256, 0, stream>>>(mask, winner);
    scatter_kernel<<<(B_ * NP_ * OUTD_ + 255) / 256, 256, 0, stream>>>(
        qkv, mask, winner, (float*)d_out);
}